// Round 1
// baseline (422.297 us; speedup 1.0000x reference)
//
#include <hip/hip_runtime.h>

typedef __bf16 bf16x8_t __attribute__((ext_vector_type(8)));
typedef float  f32x4_t  __attribute__((ext_vector_type(4)));
typedef float  floatx4  __attribute__((ext_vector_type(4)));
typedef unsigned short ushortx4 __attribute__((ext_vector_type(4)));

__device__ __forceinline__ float bf2f(unsigned short u) {
    union { unsigned int i; float f; } c; c.i = ((unsigned int)u) << 16; return c.f;
}
__device__ __forceinline__ unsigned short f2bf(float f) {
    union { float f; unsigned int i; } c; c.f = f;
    unsigned int u = c.i;
    u += 0x7fffu + ((u >> 16) & 1u);   // RNE
    return (unsigned short)(u >> 16);
}
__device__ __forceinline__ void unpack8(uint4 u, float* dst, float sc) {
    dst[0] = bf2f((unsigned short)(u.x & 0xffff)) * sc;
    dst[1] = bf2f((unsigned short)(u.x >> 16)) * sc;
    dst[2] = bf2f((unsigned short)(u.y & 0xffff)) * sc;
    dst[3] = bf2f((unsigned short)(u.y >> 16)) * sc;
    dst[4] = bf2f((unsigned short)(u.z & 0xffff)) * sc;
    dst[5] = bf2f((unsigned short)(u.z >> 16)) * sc;
    dst[6] = bf2f((unsigned short)(u.w & 0xffff)) * sc;
    dst[7] = bf2f((unsigned short)(u.w >> 16)) * sc;
}

// async global->LDS, 16 B per lane; lds dest = wave-uniform base + lane*16
__device__ __forceinline__ void load_lds16(const unsigned short* g, unsigned short* l) {
    __builtin_amdgcn_global_load_lds(
        (const __attribute__((address_space(1))) unsigned int*)g,
        (__attribute__((address_space(3))) unsigned int*)l, 16, 0, 0);
}

// ---------------------------------------------------------------------------
// x (f32) -> bf16, 8 elems/thread
// ---------------------------------------------------------------------------
__global__ __launch_bounds__(256) void convert_f32_bf16(
    const float* __restrict__ x, unsigned short* __restrict__ xb)
{
    size_t i = ((size_t)blockIdx.x * 256 + threadIdx.x) * 8;
    floatx4 a = *reinterpret_cast<const floatx4*>(x + i);
    floatx4 b = *reinterpret_cast<const floatx4*>(x + i + 4);
    uint4 o;
    o.x = (unsigned int)f2bf(a.x) | ((unsigned int)f2bf(a.y) << 16);
    o.y = (unsigned int)f2bf(a.z) | ((unsigned int)f2bf(a.w) << 16);
    o.z = (unsigned int)f2bf(b.x) | ((unsigned int)f2bf(b.y) << 16);
    o.w = (unsigned int)f2bf(b.z) | ((unsigned int)f2bf(b.w) << 16);
    *reinterpret_cast<uint4*>(xb + i) = o;
}

// ---------------------------------------------------------------------------
// Weight prep: Wt[n][k] (bf16) = W[k][n] (f32). 32x32 LDS-tiled transpose.
// ---------------------------------------------------------------------------
__global__ __launch_bounds__(256) void transpose_f32_to_bf16(
    const float* __restrict__ W, unsigned short* __restrict__ Wt,
    int Kdim, int Ndim)
{
    __shared__ float tile[32][33];
    const int n0 = blockIdx.x * 32, k0 = blockIdx.y * 32;
    const int tx = threadIdx.x & 31, ty = threadIdx.x >> 5;   // ty 0..7
#pragma unroll
    for (int r = 0; r < 4; ++r) {
        int k = ty + r * 8;
        tile[k][tx] = W[(size_t)(k0 + k) * Ndim + n0 + tx];
    }
    __syncthreads();
#pragma unroll
    for (int r = 0; r < 4; ++r) {
        int n = ty + r * 8;
        Wt[(size_t)(n0 + n) * Kdim + k0 + tx] = f2bf(tile[tx][n]);
    }
}

// ---------------------------------------------------------------------------
// 256x256-tile, 8-wave (2Mx4N), BK=32, 4-deep counted-vmcnt pipeline.
//  - LDS ring: 4 buffers x (A 16KB + B 16KB) = 128 KiB, 1 block/CU.
//  - iter t stages tile t+3 (one 8KB chunk per phase, 4 phases/tile) into
//    buf[(t+3)&3] = buf[(t-1)&3] (tile t-1's reads completed at its end barrier).
//  - vmcnt(8) once per tile (FIFO: newest 8 = tiles t+2,t+3 -> tile t+1 landed);
//    tail drains 4 -> 0. NEVER a mid-loop vmcnt(0): prefetch stays in flight
//    across barriers (T4). Raw s_barrier (no compiler vmcnt(0) drain).
//  - XOR swizzle identical to the R6-proven one (0 bank conflicts measured):
//    stage col c_sw = ((tid&3)^((tid>>3)&3))*8, read chunk xq = (quad^((lr>>1)&3))*8.
//  - setprio(1) around the 8-MFMA cluster (T5); sched_barrier(0) pins phase
//    boundaries (rule #18: inline-asm lgkmcnt needs a following sched_barrier).
// Requires: M%256==0, N%256==0, K%32==0, K>=128.
// ---------------------------------------------------------------------------
#define TBM 256
#define TBN 256
#define TBK 32

template<bool C_F32>
__global__ __launch_bounds__(512, 2) void gemm_pipe_kernel(
    const unsigned short* __restrict__ A, const unsigned short* __restrict__ Wt,
    const float* __restrict__ bias, void* __restrict__ Cp,
    int N, int K, int lda, int ldc)
{
    __shared__ __align__(16) unsigned short As[4][TBM * TBK];   // 64 KiB
    __shared__ __align__(16) unsigned short Bs[4][TBN * TBK];   // 64 KiB

    const int tid  = threadIdx.x;
    const int lane = tid & 63;
    const int wid  = tid >> 6;        // 0..7
    const int wm   = wid >> 2;        // 0..1  (M half: 128 rows)
    const int wn   = wid & 3;         // 0..3  (N quarter: 64 cols)
    const int quad = lane >> 4;       // 0..3
    const int lr   = lane & 15;       // 0..15

    const int m0 = blockIdx.y * TBM;
    const int n0 = blockIdx.x * TBN;

    const int s_row = tid >> 2;                                  // 0..127
    const int c_sw  = ((tid & 3) ^ ((tid >> 3) & 3)) * 8;        // swizzled source chunk
    const int xq    = (quad ^ ((lr >> 1) & 3)) * 8;              // swizzled read chunk
    const int NT    = K >> 5;

    // global row bases for staging (piece 0 = rows 0..127, piece 1 = rows 128..255)
    const unsigned short* Ag  = A  + (size_t)(m0 + s_row) * lda + c_sw;
    const unsigned short* Ag2 = Ag + (size_t)128 * lda;
    const unsigned short* Bg  = Wt + (size_t)(n0 + s_row) * K + c_sw;
    const unsigned short* Bg2 = Bg + (size_t)128 * K;

    f32x4_t acc[8][4];
#pragma unroll
    for (int i = 0; i < 8; ++i)
#pragma unroll
        for (int j = 0; j < 4; ++j)
            acc[i][j] = (f32x4_t){0.f, 0.f, 0.f, 0.f};

    // ---- prologue: stage tiles 0,1,2 (12 issues/wave), wait tile 0 ----
#pragma unroll
    for (int tt = 0; tt < 3; ++tt) {
        load_lds16(Ag  + tt * TBK, &As[tt][wid * 512]);
        load_lds16(Ag2 + tt * TBK, &As[tt][4096 + wid * 512]);
        load_lds16(Bg  + tt * TBK, &Bs[tt][wid * 512]);
        load_lds16(Bg2 + tt * TBK, &Bs[tt][4096 + wid * 512]);
    }
    asm volatile("s_waitcnt vmcnt(8)" ::: "memory");   // tile 0 landed (own slice)
    __builtin_amdgcn_s_barrier();                      // -> all waves' slices landed
    __builtin_amdgcn_sched_barrier(0);

    for (int tt = 0; tt < NT; ++tt) {
        const int b = tt & 3;
        const unsigned short* pa = &As[b][0];
        const unsigned short* pb = &Bs[b][0];
        const bool st = (tt + 3) < NT;
        const int  ts = tt + 3;
        const int  sb = ts & 3;
        bf16x8_t bv[4];

#pragma unroll
        for (int q = 0; q < 4; ++q) {
            // --- phase q: ds-load subtile + 1 staging chunk of tile ts ---
            bf16x8_t a0 = *reinterpret_cast<const bf16x8_t*>(
                pa + (wm * 128 + q * 32 + lr) * TBK + xq);
            bf16x8_t a1 = *reinterpret_cast<const bf16x8_t*>(
                pa + (wm * 128 + q * 32 + 16 + lr) * TBK + xq);
            if (q == 0) {
#pragma unroll
                for (int j = 0; j < 4; ++j)
                    bv[j] = *reinterpret_cast<const bf16x8_t*>(
                        pb + (wn * 64 + j * 16 + lr) * TBK + xq);
            }
            if (st) {
                if      (q == 0) load_lds16(Ag  + ts * TBK, &As[sb][wid * 512]);
                else if (q == 1) load_lds16(Ag2 + ts * TBK, &As[sb][4096 + wid * 512]);
                else if (q == 2) load_lds16(Bg  + ts * TBK, &Bs[sb][wid * 512]);
                else             load_lds16(Bg2 + ts * TBK, &Bs[sb][4096 + wid * 512]);
            }
            __builtin_amdgcn_sched_barrier(0);
            __builtin_amdgcn_s_barrier();
            asm volatile("s_waitcnt lgkmcnt(0)" ::: "memory");
            __builtin_amdgcn_sched_barrier(0);

            __builtin_amdgcn_s_setprio(1);
#pragma unroll
            for (int j = 0; j < 4; ++j) {
                acc[2 * q    ][j] = __builtin_amdgcn_mfma_f32_16x16x32_bf16(a0, bv[j], acc[2 * q    ][j], 0, 0, 0);
                acc[2 * q + 1][j] = __builtin_amdgcn_mfma_f32_16x16x32_bf16(a1, bv[j], acc[2 * q + 1][j], 0, 0, 0);
            }
            __builtin_amdgcn_s_setprio(0);
            __builtin_amdgcn_sched_barrier(0);

            if (q == 3) {   // tile boundary: counted drain, never 0 mid-loop
                if (tt < NT - 3)       asm volatile("s_waitcnt vmcnt(8)" ::: "memory");
                else if (tt == NT - 3) asm volatile("s_waitcnt vmcnt(4)" ::: "memory");
                else                   asm volatile("s_waitcnt vmcnt(0)" ::: "memory");
            }
            __builtin_amdgcn_s_barrier();
        }
    }

    // ---- epilogue ----
#pragma unroll
    for (int j = 0; j < 4; ++j) {
        int col = n0 + wn * 64 + j * 16 + lr;
        float bj = bias[col];
#pragma unroll
        for (int i = 0; i < 8; ++i) {
            int rbase = m0 + wm * 128 + i * 16 + quad * 4;
#pragma unroll
            for (int r = 0; r < 4; ++r) {
                float v = acc[i][j][r] + bj;
                size_t idx = (size_t)(rbase + r) * ldc + col;
                if (C_F32) ((float*)Cp)[idx] = v;
                else       ((unsigned short*)Cp)[idx] = f2bf(v);
            }
        }
    }
}

// ---------------------------------------------------------------------------
// Fallback GEMM (R3/R4-proven): padded LDS, regular staging.
// ---------------------------------------------------------------------------
#define BM 128
#define BN 128
#define BK 32
#define LDT 40

template<bool A_F32, bool C_F32, bool BT>
__global__ __launch_bounds__(256) void gemm_bias_kernel(
    const void* __restrict__ Ap, const void* __restrict__ Wp,
    const float* __restrict__ bias, void* __restrict__ Cp,
    int N, int K, int lda, int ldc)
{
    __shared__ __align__(16) unsigned short As[BM * LDT];
    __shared__ __align__(16) unsigned short Bs[BN * LDT];

    const int tid  = threadIdx.x;
    const int lane = tid & 63;
    const int wid  = tid >> 6;
    const int wm   = wid >> 1;
    const int wn   = wid & 1;
    const int quad = lane >> 4;
    const int lr   = lane & 15;

    const int m0 = blockIdx.y * BM;
    const int n0 = blockIdx.x * BN;

    f32x4_t acc[4][4];
#pragma unroll
    for (int i = 0; i < 4; ++i)
#pragma unroll
        for (int j = 0; j < 4; ++j)
            acc[i][j] = (f32x4_t){0.f, 0.f, 0.f, 0.f};

    for (int k0 = 0; k0 < K; k0 += BK) {
        if (A_F32) {
            const float* A = (const float*)Ap;
#pragma unroll
            for (int it = 0; it < 4; ++it) {
                int q   = tid + it * 256;
                int row = q >> 3;
                int col = (q & 7) * 4;
                floatx4 f = *reinterpret_cast<const floatx4*>(A + (size_t)(m0 + row) * lda + k0 + col);
                ushortx4 s;
                s.x = f2bf(f.x); s.y = f2bf(f.y); s.z = f2bf(f.z); s.w = f2bf(f.w);
                *reinterpret_cast<ushortx4*>(&As[row * LDT + col]) = s;
            }
        } else {
            const unsigned short* A = (const unsigned short*)Ap;
            int a_row = tid >> 2;
            int a_col = (tid & 3) * 8;
#pragma unroll
            for (int r = 0; r < 2; ++r) {
                int row = a_row + r * 64;
                uint4 u = *reinterpret_cast<const uint4*>(A + (size_t)(m0 + row) * lda + k0 + a_col);
                *reinterpret_cast<uint4*>(&As[row * LDT + a_col]) = u;
            }
        }
        if (BT) {
            const unsigned short* Wt = (const unsigned short*)Wp;
            int b_row = tid >> 2;
            int b_col = (tid & 3) * 8;
#pragma unroll
            for (int r = 0; r < 2; ++r) {
                int n = b_row + r * 64;
                uint4 u = *reinterpret_cast<const uint4*>(Wt + (size_t)(n0 + n) * K + k0 + b_col);
                *reinterpret_cast<uint4*>(&Bs[n * LDT + b_col]) = u;
            }
        } else {
            const float* W = (const float*)Wp;
#pragma unroll
            for (int it = 0; it < 4; ++it) {
                int q  = tid + it * 256;
                int kk = q >> 5;
                int nn = (q & 31) * 4;
                floatx4 f = *reinterpret_cast<const floatx4*>(W + (size_t)(k0 + kk) * N + n0 + nn);
                Bs[(nn + 0) * LDT + kk] = f2bf(f.x);
                Bs[(nn + 1) * LDT + kk] = f2bf(f.y);
                Bs[(nn + 2) * LDT + kk] = f2bf(f.z);
                Bs[(nn + 3) * LDT + kk] = f2bf(f.w);
            }
        }
        __syncthreads();

        bf16x8_t av[4], bv[4];
#pragma unroll
        for (int i = 0; i < 4; ++i)
            av[i] = *reinterpret_cast<const bf16x8_t*>(&As[(wm * 64 + i * 16 + lr) * LDT + quad * 8]);
#pragma unroll
        for (int j = 0; j < 4; ++j)
            bv[j] = *reinterpret_cast<const bf16x8_t*>(&Bs[(wn * 64 + j * 16 + lr) * LDT + quad * 8]);

#pragma unroll
        for (int i = 0; i < 4; ++i)
#pragma unroll
            for (int j = 0; j < 4; ++j)
                acc[i][j] = __builtin_amdgcn_mfma_f32_16x16x32_bf16(av[i], bv[j], acc[i][j], 0, 0, 0);

        __syncthreads();
    }

#pragma unroll
    for (int j = 0; j < 4; ++j) {
        int col = n0 + wn * 64 + j * 16 + lr;
        float bj = bias[col];
#pragma unroll
        for (int i = 0; i < 4; ++i) {
            int rbase = m0 + wm * 64 + i * 16 + quad * 4;
#pragma unroll
            for (int r = 0; r < 4; ++r) {
                float v = acc[i][j][r] + bj;
                size_t idx = (size_t)(rbase + r) * ldc + col;
                if (C_F32) ((float*)Cp)[idx] = v;
                else       ((unsigned short*)Cp)[idx] = f2bf(v);
            }
        }
    }
}

// ---------------------------------------------------------------------------
// Tiled neighborhood attention v2 (unchanged this round; R6-verified).
// ---------------------------------------------------------------------------
#define NA_L 4096
#define NA_K 13
#define NA_H 16
#define NA_D 64
#define NA_SCALE 0.125f
#define TL  64
#define WIN 76          // TL + 12
#define KD  68          // padded f32 row (17 float4 chunks)

__global__ __launch_bounds__(256) void na1d_tiled_kernel(
    unsigned short* qkv, const float* __restrict__ rpb)
{
    __shared__ __align__(16) float ks[WIN * KD];
    __shared__ __align__(16) float vs[WIN * KD];
    __shared__ __align__(16) float qs[TL * KD];
    __shared__ float wgt[TL][NA_K];

    const int bid = blockIdx.x;
    const int h  = bid & 15;
    const int lt = (bid >> 4) & 63;
    const int b  = bid >> 10;
    const int l0 = lt * TL;
    const int rs = l0 - 6;

    const int t = threadIdx.x;
    const size_t rowbase = (size_t)b * NA_L;

    // ---- phase 1: prefetch q + k/v window, then unpack to LDS ----
    {
        const int qr = t >> 2;
        const int qc = (t & 3) * 16;
        const unsigned short* qsrc = qkv + (rowbase + l0 + qr) * 3072 + h * 64 + qc;
        uint4 q0 = *reinterpret_cast<const uint4*>(qsrc);
        uint4 q1 = *reinterpret_cast<const uint4*>(qsrc + 8);

        const int r0 = t >> 3;            // 0..31
        const int cc = (t & 7) * 8;
        int g0 = rs + r0;      g0 = g0 < 0 ? 0 : (g0 > NA_L - 1 ? NA_L - 1 : g0);
        int g1 = rs + r0 + 32; g1 = g1 < 0 ? 0 : (g1 > NA_L - 1 ? NA_L - 1 : g1);
        const unsigned short* p0 = qkv + (rowbase + g0) * 3072 + 1024 + h * 64 + cc;
        const unsigned short* p1 = qkv + (rowbase + g1) * 3072 + 1024 + h * 64 + cc;
        uint4 k0 = *reinterpret_cast<const uint4*>(p0);
        uint4 v0 = *reinterpret_cast<const uint4*>(p0 + 1024);
        uint4 k1 = *reinterpret_cast<const uint4*>(p1);
        uint4 v1 = *reinterpret_cast<const uint4*>(p1 + 1024);
        uint4 k2, v2;
        if (t < 96) {
            int g2 = rs + r0 + 64; g2 = g2 < 0 ? 0 : (g2 > NA_L - 1 ? NA_L - 1 : g2);
            const unsigned short* p2 = qkv + (rowbase + g2) * 3072 + 1024 + h * 64 + cc;
            k2 = *reinterpret_cast<const uint4*>(p2);
            v2 = *reinterpret_cast<const uint4*>(p2 + 1024);
        }

        unpack8(q0, &qs[qr * KD + qc], NA_SCALE);
        unpack8(q1, &qs[qr * KD + qc + 8], NA_SCALE);
        unpack8(k0, &ks[r0 * KD + cc], 1.f);
        unpack8(v0, &vs[r0 * KD + cc], 1.f);
        unpack8(k1, &ks[(r0 + 32) * KD + cc], 1.f);
        unpack8(v1, &vs[(r0 + 32) * KD + cc], 1.f);
        if (t < 96) {
            unpack8(k2, &ks[(r0 + 64) * KD + cc], 1.f);
            unpack8(v2, &vs[(r0 + 64) * KD + cc], 1.f);
        }
    }
    __syncthreads();

    // ---- phase 2: logits; wave jb handles j = 4jb..4jb+3 for lane's l ----
    {
        const int l  = t & 63;
        const int jb = (t >> 6) * 4;
        int ig = l0 + l;
        int ni = ig - 6;
        if (ni < 0) ni = 0;
        if (ni > NA_L - NA_K) ni = NA_L - NA_K;
        int rid = ni - rs;                    // 0..57
        int pi  = ni - ig + 12;
        const floatx4* qr = reinterpret_cast<const floatx4*>(&qs[l * KD]);
        const floatx4* k0 = reinterpret_cast<const floatx4*>(&ks[(rid + jb + 0) * KD]);
        const floatx4* k1 = reinterpret_cast<const floatx4*>(&ks[(rid + jb + 1) * KD]);
        const floatx4* k2 = reinterpret_cast<const floatx4*>(&ks[(rid + jb + 2) * KD]);
        const floatx4* k3 = reinterpret_cast<const floatx4*>(&ks[(rid + jb + 3) * KD]);
        floatx4 a0 = {0,0,0,0}, a1 = {0,0,0,0}, a2 = {0,0,0,0}, a3 = {0,0,0,0};
#pragma unroll
        for (int c = 0; c < 16; ++c) {
            floatx4 qv = qr[c];
            a0 += qv * k0[c];
            a1 += qv * k1[c];
            a2 += qv * k2[c];
            a3 += qv * k3[c];
        }
        float s0 = a0.x + a0.y + a0.z + a0.w;
        float s1 = a1.x + a1.y + a1.z + a1.w;
        float s2 = a2.x + a2.y + a2.z + a2.w;
        float s3 = a3.x + a3.y + a3.z + a3.w;
        const float* rp = rpb + h * 25 + pi;
        if (jb + 0 < NA_K) wgt[l][jb + 0] = s0 + rp[jb + 0];
        if (jb + 1 < NA_K) wgt[l][jb + 1] = s1 + rp[jb + 1];
        if (jb + 2 < NA_K) wgt[l][jb + 2] = s2 + rp[jb + 2];
        if (jb + 3 < NA_K) wgt[l][jb + 3] = s3 + rp[jb + 3];
    }
    __syncthreads();

    // ---- phase 3: softmax per l ----
    if (t < TL) {
        float m = -1e30f;
#pragma unroll
        for (int j = 0; j < NA_K; ++j) m = fmaxf(m, wgt[t][j]);
        float sum = 0.f;
#pragma unroll
        for (int j = 0; j < NA_K; ++j) {
            float e = expf(wgt[t][j] - m);
            wgt[t][j] = e;
            sum += e;
        }
        float inv = 1.f / sum;
#pragma unroll
        for (int j = 0; j < NA_K; ++j) wgt[t][j] *= inv;
    }
    __syncthreads();

    // ---- phase 4: AV. thread (l, 16-d chunk), float4 reads ----
    {
        const int l  = t & 63;
        const int d0 = (t >> 6) * 16;
        int ig = l0 + l;
        int ni = ig - 6;
        if (ni < 0) ni = 0;
        if (ni > NA_L - NA_K) ni = NA_L - NA_K;
        int rid = ni - rs;
        floatx4 o0 = {0,0,0,0}, o1 = {0,0,0,0}, o2 = {0,0,0,0}, o3 = {0,0,0,0};
#pragma unroll
        for (int j = 0; j < NA_K; ++j) {
            float w = wgt[l][j];
            const floatx4* vr = reinterpret_cast<const floatx4*>(&vs[(rid + j) * KD + d0]);
            o0 += w * vr[0];
            o1 += w * vr[1];
            o2 += w * vr[2];
            o3 += w * vr[3];
        }
        unsigned short* dst = qkv + (rowbase + ig) * 3072 + h * 64 + d0;
        uint4 p0, p1;
        p0.x = (unsigned int)f2bf(o0.x) | ((unsigned int)f2bf(o0.y) << 16);
        p0.y = (unsigned int)f2bf(o0.z) | ((unsigned int)f2bf(o0.w) << 16);
        p0.z = (unsigned int)f2bf(o1.x) | ((unsigned int)f2bf(o1.y) << 16);
        p0.w = (unsigned int)f2bf(o1.z) | ((unsigned int)f2bf(o1.w) << 16);
        p1.x = (unsigned int)f2bf(o2.x) | ((unsigned int)f2bf(o2.y) << 16);
        p1.y = (unsigned int)f2bf(o2.z) | ((unsigned int)f2bf(o2.w) << 16);
        p1.z = (unsigned int)f2bf(o3.x) | ((unsigned int)f2bf(o3.y) << 16);
        p1.w = (unsigned int)f2bf(o3.z) | ((unsigned int)f2bf(o3.w) << 16);
        *reinterpret_cast<uint4*>(dst)     = p0;
        *reinterpret_cast<uint4*>(dst + 8) = p1;
    }
}

// ---------------------------------------------------------------------------
extern "C" void kernel_launch(void* const* d_in, const int* in_sizes, int n_in,
                              void* d_out, int out_size, void* d_ws, size_t ws_size,
                              hipStream_t stream)
{
    const float* x      = (const float*)d_in[0];
    const float* w_qkv  = (const float*)d_in[1];
    const float* b_qkv  = (const float*)d_in[2];
    const float* rpb    = (const float*)d_in[3];
    const float* w_proj = (const float*)d_in[4];
    const float* b_proj = (const float*)d_in[5];
    float* out = (float*)d_out;

    const int M  = 4 * 4096;   // 16384
    const int K  = 1024;
    const int N1 = 3072;
    const int N2 = 1024;

    unsigned short* qkv = (unsigned short*)d_ws;              // 96 MiB
    unsigned short* Wt1 = qkv + (size_t)M * N1;               // 6 MiB
    unsigned short* Wt2 = Wt1 + (size_t)N1 * K;               // 2 MiB
    unsigned short* xb  = Wt2 + (size_t)N2 * K;               // 32 MiB
    size_t need_mid  = ((size_t)M * N1 + (size_t)N1 * K + (size_t)N2 * K) * 2;
    size_t need_fast = need_mid + (size_t)M * K * 2;

    const int na_grid = 4 * (NA_L / TL) * NA_H;               // 4096

    if (ws_size >= need_fast) {
        convert_f32_bf16<<<dim3(M * K / (256 * 8)), 256, 0, stream>>>(x, xb);
        transpose_f32_to_bf16<<<dim3(N1 / 32, K / 32), 256, 0, stream>>>(w_qkv, Wt1, K, N1);
        transpose_f32_to_bf16<<<dim3(N2 / 32, K / 32), 256, 0, stream>>>(w_proj, Wt2, K, N2);
        gemm_pipe_kernel<false><<<dim3(N1 / TBN, M / TBM), 512, 0, stream>>>(
            xb, Wt1, b_qkv, qkv, N1, K, K, N1);
        na1d_tiled_kernel<<<dim3(na_grid), 256, 0, stream>>>(qkv, rpb);
        gemm_pipe_kernel<true><<<dim3(N2 / TBN, M / TBM), 512, 0, stream>>>(
            qkv, Wt2, b_proj, out, N2, K, N1, N2);
    } else if (ws_size >= need_mid) {
        transpose_f32_to_bf16<<<dim3(N1 / 32, K / 32), 256, 0, stream>>>(w_qkv, Wt1, K, N1);
        transpose_f32_to_bf16<<<dim3(N2 / 32, K / 32), 256, 0, stream>>>(w_proj, Wt2, K, N2);
        gemm_bias_kernel<true, false, true><<<dim3(N1 / BN, M / BM), 256, 0, stream>>>(
            x, Wt1, b_qkv, qkv, N1, K, K, N1);
        na1d_tiled_kernel<<<dim3(na_grid), 256, 0, stream>>>(qkv, rpb);
        gemm_bias_kernel<false, true, true><<<dim3(N2 / BN, M / BM), 256, 0, stream>>>(
            qkv, Wt2, b_proj, out, N2, K, N1, N2);
    } else {
        gemm_bias_kernel<true, false, false><<<dim3(N1 / BN, M / BM), 256, 0, stream>>>(
            x, w_qkv, b_qkv, qkv, N1, K, K, N1);
        na1d_tiled_kernel<<<dim3(na_grid), 256, 0, stream>>>(qkv, rpb);
        gemm_bias_kernel<false, true, false><<<dim3(N2 / BN, M / BM), 256, 0, stream>>>(
            qkv, w_proj, b_proj, out, N2, K, N1, N2);
    }
}

// Round 2
// 386.039 us; speedup vs baseline: 1.0939x; 1.0939x over previous
//
#include <hip/hip_runtime.h>

typedef __bf16 bf16x8_t __attribute__((ext_vector_type(8)));
typedef float  f32x4_t  __attribute__((ext_vector_type(4)));
typedef float  floatx4  __attribute__((ext_vector_type(4)));
typedef unsigned short ushortx4 __attribute__((ext_vector_type(4)));

__device__ __forceinline__ float bf2f(unsigned short u) {
    union { unsigned int i; float f; } c; c.i = ((unsigned int)u) << 16; return c.f;
}
__device__ __forceinline__ unsigned short f2bf(float f) {
    union { float f; unsigned int i; } c; c.f = f;
    unsigned int u = c.i;
    u += 0x7fffu + ((u >> 16) & 1u);   // RNE
    return (unsigned short)(u >> 16);
}
__device__ __forceinline__ void unpack8(uint4 u, float* dst, float sc) {
    dst[0] = bf2f((unsigned short)(u.x & 0xffff)) * sc;
    dst[1] = bf2f((unsigned short)(u.x >> 16)) * sc;
    dst[2] = bf2f((unsigned short)(u.y & 0xffff)) * sc;
    dst[3] = bf2f((unsigned short)(u.y >> 16)) * sc;
    dst[4] = bf2f((unsigned short)(u.z & 0xffff)) * sc;
    dst[5] = bf2f((unsigned short)(u.z >> 16)) * sc;
    dst[6] = bf2f((unsigned short)(u.w & 0xffff)) * sc;
    dst[7] = bf2f((unsigned short)(u.w >> 16)) * sc;
}

// async global->LDS, 16 B per lane; lds dest = wave-uniform base + lane*16
__device__ __forceinline__ void load_lds16(const unsigned short* g, unsigned short* l) {
    __builtin_amdgcn_global_load_lds(
        (const __attribute__((address_space(1))) unsigned int*)g,
        (__attribute__((address_space(3))) unsigned int*)l, 16, 0, 0);
}

// ---------------------------------------------------------------------------
// x (f32) -> bf16, 8 elems/thread
// ---------------------------------------------------------------------------
__global__ __launch_bounds__(256) void convert_f32_bf16(
    const float* __restrict__ x, unsigned short* __restrict__ xb)
{
    size_t i = ((size_t)blockIdx.x * 256 + threadIdx.x) * 8;
    floatx4 a = *reinterpret_cast<const floatx4*>(x + i);
    floatx4 b = *reinterpret_cast<const floatx4*>(x + i + 4);
    uint4 o;
    o.x = (unsigned int)f2bf(a.x) | ((unsigned int)f2bf(a.y) << 16);
    o.y = (unsigned int)f2bf(a.z) | ((unsigned int)f2bf(a.w) << 16);
    o.z = (unsigned int)f2bf(b.x) | ((unsigned int)f2bf(b.y) << 16);
    o.w = (unsigned int)f2bf(b.z) | ((unsigned int)f2bf(b.w) << 16);
    *reinterpret_cast<uint4*>(xb + i) = o;
}

// ---------------------------------------------------------------------------
// Weight prep: Wt[n][k] (bf16) = W[k][n] (f32). 32x32 LDS-tiled transpose.
// ---------------------------------------------------------------------------
__global__ __launch_bounds__(256) void transpose_f32_to_bf16(
    const float* __restrict__ W, unsigned short* __restrict__ Wt,
    int Kdim, int Ndim)
{
    __shared__ float tile[32][33];
    const int n0 = blockIdx.x * 32, k0 = blockIdx.y * 32;
    const int tx = threadIdx.x & 31, ty = threadIdx.x >> 5;   // ty 0..7
#pragma unroll
    for (int r = 0; r < 4; ++r) {
        int k = ty + r * 8;
        tile[k][tx] = W[(size_t)(k0 + k) * Ndim + n0 + tx];
    }
    __syncthreads();
#pragma unroll
    for (int r = 0; r < 4; ++r) {
        int n = ty + r * 8;
        Wt[(size_t)(n0 + n) * Kdim + k0 + tx] = f2bf(tile[tx][n]);
    }
}

// ---------------------------------------------------------------------------
// 256x256-tile, 8-wave (2Mx4N), BK=32, 4-deep counted-vmcnt ring. v2:
//  - FAT phases: 2 phases per K-tile, 16 MFMA each (was 4 phases x 8 MFMA).
//    Barriers: 3 per K-tile (pre-MFMA x2 + boundary), was 8.
//  - NO sched_barrier / explicit lgkmcnt: ds_reads are compiler-tracked
//    (compiler emits fine lgkmcnt; m97 evidence). The vmcnt asm "memory"
//    clobber is the only ordering anchor for global_load_lds -> ds_read.
//  - ring: iter t stages tile t+3 into buf (t+3)&3 = (t-1)&3 (reads of that
//    buf finished before tile t-1's end barrier). vmcnt(8) at tile boundary
//    (newest 8 = tiles t+2,t+3 -> t+1 landed); tail 4 -> 0. Never drain 0
//    mid-loop (T4).
//  - XOR swizzle identical to R6-proven (0 bank conflicts measured).
//  - XCD-aware bijective blockIdx swizzle (T1): grid %8==0 in both call
//    sites; each XCD gets 8 consecutive M-panels (4MB A panel = one L2).
// Requires: M%256==0, N%256==0, K%32==0, K>=128, grid %8==0.
// ---------------------------------------------------------------------------
#define TBM 256
#define TBN 256
#define TBK 32

template<bool C_F32>
__global__ __launch_bounds__(512, 2) void gemm_pipe_kernel(
    const unsigned short* __restrict__ A, const unsigned short* __restrict__ Wt,
    const float* __restrict__ bias, void* __restrict__ Cp,
    int N, int K, int lda, int ldc)
{
    __shared__ __align__(16) unsigned short As[4][TBM * TBK];   // 64 KiB
    __shared__ __align__(16) unsigned short Bs[4][TBN * TBK];   // 64 KiB

    const int tid  = threadIdx.x;
    const int lane = tid & 63;
    const int wid  = tid >> 6;        // 0..7
    const int wm   = wid >> 2;        // 0..1  (M half: 128 rows)
    const int wn   = wid & 3;         // 0..3  (N quarter: 64 cols)
    const int quad = lane >> 4;       // 0..3
    const int lr   = lane & 15;       // 0..15

    // XCD-aware bijective swizzle (nwg % 8 == 0 at both call sites)
    const int gx  = gridDim.x;
    const int cpx = (gx * gridDim.y) >> 3;
    const int bid = blockIdx.y * gx + blockIdx.x;
    const int nid = (bid & 7) * cpx + (bid >> 3);
    const int m0 = (nid / gx) * TBM;
    const int n0 = (nid % gx) * TBN;

    const int s_row = tid >> 2;                                  // 0..127
    const int c_sw  = ((tid & 3) ^ ((tid >> 3) & 3)) * 8;        // swizzled source chunk
    const int xq    = (quad ^ ((lr >> 1) & 3)) * 8;              // swizzled read chunk
    const int NT    = K >> 5;

    const unsigned short* Ag  = A  + (size_t)(m0 + s_row) * lda + c_sw;
    const unsigned short* Ag2 = Ag + (size_t)128 * lda;
    const unsigned short* Bg  = Wt + (size_t)(n0 + s_row) * K + c_sw;
    const unsigned short* Bg2 = Bg + (size_t)128 * K;

    f32x4_t acc[8][4];
#pragma unroll
    for (int i = 0; i < 8; ++i)
#pragma unroll
        for (int j = 0; j < 4; ++j)
            acc[i][j] = (f32x4_t){0.f, 0.f, 0.f, 0.f};

    // ---- prologue: stage tiles 0,1,2 (12 issues/wave), wait tile 0 ----
#pragma unroll
    for (int tt = 0; tt < 3; ++tt) {
        load_lds16(Ag  + tt * TBK, &As[tt][wid * 512]);
        load_lds16(Ag2 + tt * TBK, &As[tt][4096 + wid * 512]);
        load_lds16(Bg  + tt * TBK, &Bs[tt][wid * 512]);
        load_lds16(Bg2 + tt * TBK, &Bs[tt][4096 + wid * 512]);
    }
    asm volatile("s_waitcnt vmcnt(8)" ::: "memory");   // tile 0 landed (own slice)
    __builtin_amdgcn_s_barrier();                      // -> all waves' slices landed

    for (int tt = 0; tt < NT; ++tt) {
        const int b = tt & 3;
        const unsigned short* pa = &As[b][0];
        const unsigned short* pb = &Bs[b][0];
        const bool st = (tt + 3) < NT;
        const int  sb = (tt + 3) & 3;
        const int  ko = (tt + 3) * TBK;

        // ===== phase A: frags rows 0..63 + all B-frags; stage A-chunks =====
        bf16x8_t a0 = *reinterpret_cast<const bf16x8_t*>(pa + (wm * 128 +   0 + lr) * TBK + xq);
        bf16x8_t a1 = *reinterpret_cast<const bf16x8_t*>(pa + (wm * 128 +  16 + lr) * TBK + xq);
        bf16x8_t a2 = *reinterpret_cast<const bf16x8_t*>(pa + (wm * 128 +  32 + lr) * TBK + xq);
        bf16x8_t a3 = *reinterpret_cast<const bf16x8_t*>(pa + (wm * 128 +  48 + lr) * TBK + xq);
        bf16x8_t bv[4];
#pragma unroll
        for (int j = 0; j < 4; ++j)
            bv[j] = *reinterpret_cast<const bf16x8_t*>(pb + (wn * 64 + j * 16 + lr) * TBK + xq);
        if (st) {
            load_lds16(Ag  + ko, &As[sb][wid * 512]);
            load_lds16(Ag2 + ko, &As[sb][4096 + wid * 512]);
        }
        __builtin_amdgcn_s_barrier();

        __builtin_amdgcn_s_setprio(1);
#pragma unroll
        for (int j = 0; j < 4; ++j) {
            acc[0][j] = __builtin_amdgcn_mfma_f32_16x16x32_bf16(a0, bv[j], acc[0][j], 0, 0, 0);
            acc[1][j] = __builtin_amdgcn_mfma_f32_16x16x32_bf16(a1, bv[j], acc[1][j], 0, 0, 0);
            acc[2][j] = __builtin_amdgcn_mfma_f32_16x16x32_bf16(a2, bv[j], acc[2][j], 0, 0, 0);
            acc[3][j] = __builtin_amdgcn_mfma_f32_16x16x32_bf16(a3, bv[j], acc[3][j], 0, 0, 0);
        }
        __builtin_amdgcn_s_setprio(0);

        // ===== phase B: frags rows 64..127 (reuse B-frags); stage B-chunks =====
        bf16x8_t a4 = *reinterpret_cast<const bf16x8_t*>(pa + (wm * 128 +  64 + lr) * TBK + xq);
        bf16x8_t a5 = *reinterpret_cast<const bf16x8_t*>(pa + (wm * 128 +  80 + lr) * TBK + xq);
        bf16x8_t a6 = *reinterpret_cast<const bf16x8_t*>(pa + (wm * 128 +  96 + lr) * TBK + xq);
        bf16x8_t a7 = *reinterpret_cast<const bf16x8_t*>(pa + (wm * 128 + 112 + lr) * TBK + xq);
        if (st) {
            load_lds16(Bg  + ko, &Bs[sb][wid * 512]);
            load_lds16(Bg2 + ko, &Bs[sb][4096 + wid * 512]);
        }
        __builtin_amdgcn_s_barrier();

        __builtin_amdgcn_s_setprio(1);
#pragma unroll
        for (int j = 0; j < 4; ++j) {
            acc[4][j] = __builtin_amdgcn_mfma_f32_16x16x32_bf16(a4, bv[j], acc[4][j], 0, 0, 0);
            acc[5][j] = __builtin_amdgcn_mfma_f32_16x16x32_bf16(a5, bv[j], acc[5][j], 0, 0, 0);
            acc[6][j] = __builtin_amdgcn_mfma_f32_16x16x32_bf16(a6, bv[j], acc[6][j], 0, 0, 0);
            acc[7][j] = __builtin_amdgcn_mfma_f32_16x16x32_bf16(a7, bv[j], acc[7][j], 0, 0, 0);
        }
        __builtin_amdgcn_s_setprio(0);

        // tile boundary: counted drain, never 0 mid-loop (T4)
        if (tt < NT - 3)       asm volatile("s_waitcnt vmcnt(8)" ::: "memory");
        else if (tt == NT - 3) asm volatile("s_waitcnt vmcnt(4)" ::: "memory");
        else                   asm volatile("s_waitcnt vmcnt(0)" ::: "memory");
        __builtin_amdgcn_s_barrier();
    }

    // ---- epilogue ----
#pragma unroll
    for (int j = 0; j < 4; ++j) {
        int col = n0 + wn * 64 + j * 16 + lr;
        float bj = bias[col];
#pragma unroll
        for (int i = 0; i < 8; ++i) {
            int rbase = m0 + wm * 128 + i * 16 + quad * 4;
#pragma unroll
            for (int r = 0; r < 4; ++r) {
                float v = acc[i][j][r] + bj;
                size_t idx = (size_t)(rbase + r) * ldc + col;
                if (C_F32) ((float*)Cp)[idx] = v;
                else       ((unsigned short*)Cp)[idx] = f2bf(v);
            }
        }
    }
}

// ---------------------------------------------------------------------------
// Fallback GEMM (R3/R4-proven): padded LDS, regular staging.
// ---------------------------------------------------------------------------
#define BM 128
#define BN 128
#define BK 32
#define LDT 40

template<bool A_F32, bool C_F32, bool BT>
__global__ __launch_bounds__(256) void gemm_bias_kernel(
    const void* __restrict__ Ap, const void* __restrict__ Wp,
    const float* __restrict__ bias, void* __restrict__ Cp,
    int N, int K, int lda, int ldc)
{
    __shared__ __align__(16) unsigned short As[BM * LDT];
    __shared__ __align__(16) unsigned short Bs[BN * LDT];

    const int tid  = threadIdx.x;
    const int lane = tid & 63;
    const int wid  = tid >> 6;
    const int wm   = wid >> 1;
    const int wn   = wid & 1;
    const int quad = lane >> 4;
    const int lr   = lane & 15;

    const int m0 = blockIdx.y * BM;
    const int n0 = blockIdx.x * BN;

    f32x4_t acc[4][4];
#pragma unroll
    for (int i = 0; i < 4; ++i)
#pragma unroll
        for (int j = 0; j < 4; ++j)
            acc[i][j] = (f32x4_t){0.f, 0.f, 0.f, 0.f};

    for (int k0 = 0; k0 < K; k0 += BK) {
        if (A_F32) {
            const float* A = (const float*)Ap;
#pragma unroll
            for (int it = 0; it < 4; ++it) {
                int q   = tid + it * 256;
                int row = q >> 3;
                int col = (q & 7) * 4;
                floatx4 f = *reinterpret_cast<const floatx4*>(A + (size_t)(m0 + row) * lda + k0 + col);
                ushortx4 s;
                s.x = f2bf(f.x); s.y = f2bf(f.y); s.z = f2bf(f.z); s.w = f2bf(f.w);
                *reinterpret_cast<ushortx4*>(&As[row * LDT + col]) = s;
            }
        } else {
            const unsigned short* A = (const unsigned short*)Ap;
            int a_row = tid >> 2;
            int a_col = (tid & 3) * 8;
#pragma unroll
            for (int r = 0; r < 2; ++r) {
                int row = a_row + r * 64;
                uint4 u = *reinterpret_cast<const uint4*>(A + (size_t)(m0 + row) * lda + k0 + a_col);
                *reinterpret_cast<uint4*>(&As[row * LDT + a_col]) = u;
            }
        }
        if (BT) {
            const unsigned short* Wt = (const unsigned short*)Wp;
            int b_row = tid >> 2;
            int b_col = (tid & 3) * 8;
#pragma unroll
            for (int r = 0; r < 2; ++r) {
                int n = b_row + r * 64;
                uint4 u = *reinterpret_cast<const uint4*>(Wt + (size_t)(n0 + n) * K + k0 + b_col);
                *reinterpret_cast<uint4*>(&Bs[n * LDT + b_col]) = u;
            }
        } else {
            const float* W = (const float*)Wp;
#pragma unroll
            for (int it = 0; it < 4; ++it) {
                int q  = tid + it * 256;
                int kk = q >> 5;
                int nn = (q & 31) * 4;
                floatx4 f = *reinterpret_cast<const floatx4*>(W + (size_t)(k0 + kk) * N + n0 + nn);
                Bs[(nn + 0) * LDT + kk] = f2bf(f.x);
                Bs[(nn + 1) * LDT + kk] = f2bf(f.y);
                Bs[(nn + 2) * LDT + kk] = f2bf(f.z);
                Bs[(nn + 3) * LDT + kk] = f2bf(f.w);
            }
        }
        __syncthreads();

        bf16x8_t av[4], bv[4];
#pragma unroll
        for (int i = 0; i < 4; ++i)
            av[i] = *reinterpret_cast<const bf16x8_t*>(&As[(wm * 64 + i * 16 + lr) * LDT + quad * 8]);
#pragma unroll
        for (int j = 0; j < 4; ++j)
            bv[j] = *reinterpret_cast<const bf16x8_t*>(&Bs[(wn * 64 + j * 16 + lr) * LDT + quad * 8]);

#pragma unroll
        for (int i = 0; i < 4; ++i)
#pragma unroll
            for (int j = 0; j < 4; ++j)
                acc[i][j] = __builtin_amdgcn_mfma_f32_16x16x32_bf16(av[i], bv[j], acc[i][j], 0, 0, 0);

        __syncthreads();
    }

#pragma unroll
    for (int j = 0; j < 4; ++j) {
        int col = n0 + wn * 64 + j * 16 + lr;
        float bj = bias[col];
#pragma unroll
        for (int i = 0; i < 4; ++i) {
            int rbase = m0 + wm * 64 + i * 16 + quad * 4;
#pragma unroll
            for (int r = 0; r < 4; ++r) {
                float v = acc[i][j][r] + bj;
                size_t idx = (size_t)(rbase + r) * ldc + col;
                if (C_F32) ((float*)Cp)[idx] = v;
                else       ((unsigned short*)Cp)[idx] = f2bf(v);
            }
        }
    }
}

// ---------------------------------------------------------------------------
// Tiled neighborhood attention v2 (unchanged this round; R6-verified).
// ---------------------------------------------------------------------------
#define NA_L 4096
#define NA_K 13
#define NA_H 16
#define NA_D 64
#define NA_SCALE 0.125f
#define TL  64
#define WIN 76          // TL + 12
#define KD  68          // padded f32 row (17 float4 chunks)

__global__ __launch_bounds__(256) void na1d_tiled_kernel(
    unsigned short* qkv, const float* __restrict__ rpb)
{
    __shared__ __align__(16) float ks[WIN * KD];
    __shared__ __align__(16) float vs[WIN * KD];
    __shared__ __align__(16) float qs[TL * KD];
    __shared__ float wgt[TL][NA_K];

    const int bid = blockIdx.x;
    const int h  = bid & 15;
    const int lt = (bid >> 4) & 63;
    const int b  = bid >> 10;
    const int l0 = lt * TL;
    const int rs = l0 - 6;

    const int t = threadIdx.x;
    const size_t rowbase = (size_t)b * NA_L;

    // ---- phase 1: prefetch q + k/v window, then unpack to LDS ----
    {
        const int qr = t >> 2;
        const int qc = (t & 3) * 16;
        const unsigned short* qsrc = qkv + (rowbase + l0 + qr) * 3072 + h * 64 + qc;
        uint4 q0 = *reinterpret_cast<const uint4*>(qsrc);
        uint4 q1 = *reinterpret_cast<const uint4*>(qsrc + 8);

        const int r0 = t >> 3;            // 0..31
        const int cc = (t & 7) * 8;
        int g0 = rs + r0;      g0 = g0 < 0 ? 0 : (g0 > NA_L - 1 ? NA_L - 1 : g0);
        int g1 = rs + r0 + 32; g1 = g1 < 0 ? 0 : (g1 > NA_L - 1 ? NA_L - 1 : g1);
        const unsigned short* p0 = qkv + (rowbase + g0) * 3072 + 1024 + h * 64 + cc;
        const unsigned short* p1 = qkv + (rowbase + g1) * 3072 + 1024 + h * 64 + cc;
        uint4 k0 = *reinterpret_cast<const uint4*>(p0);
        uint4 v0 = *reinterpret_cast<const uint4*>(p0 + 1024);
        uint4 k1 = *reinterpret_cast<const uint4*>(p1);
        uint4 v1 = *reinterpret_cast<const uint4*>(p1 + 1024);
        uint4 k2, v2;
        if (t < 96) {
            int g2 = rs + r0 + 64; g2 = g2 < 0 ? 0 : (g2 > NA_L - 1 ? NA_L - 1 : g2);
            const unsigned short* p2 = qkv + (rowbase + g2) * 3072 + 1024 + h * 64 + cc;
            k2 = *reinterpret_cast<const uint4*>(p2);
            v2 = *reinterpret_cast<const uint4*>(p2 + 1024);
        }

        unpack8(q0, &qs[qr * KD + qc], NA_SCALE);
        unpack8(q1, &qs[qr * KD + qc + 8], NA_SCALE);
        unpack8(k0, &ks[r0 * KD + cc], 1.f);
        unpack8(v0, &vs[r0 * KD + cc], 1.f);
        unpack8(k1, &ks[(r0 + 32) * KD + cc], 1.f);
        unpack8(v1, &vs[(r0 + 32) * KD + cc], 1.f);
        if (t < 96) {
            unpack8(k2, &ks[(r0 + 64) * KD + cc], 1.f);
            unpack8(v2, &vs[(r0 + 64) * KD + cc], 1.f);
        }
    }
    __syncthreads();

    // ---- phase 2: logits; wave jb handles j = 4jb..4jb+3 for lane's l ----
    {
        const int l  = t & 63;
        const int jb = (t >> 6) * 4;
        int ig = l0 + l;
        int ni = ig - 6;
        if (ni < 0) ni = 0;
        if (ni > NA_L - NA_K) ni = NA_L - NA_K;
        int rid = ni - rs;                    // 0..57
        int pi  = ni - ig + 12;
        const floatx4* qr = reinterpret_cast<const floatx4*>(&qs[l * KD]);
        const floatx4* k0 = reinterpret_cast<const floatx4*>(&ks[(rid + jb + 0) * KD]);
        const floatx4* k1 = reinterpret_cast<const floatx4*>(&ks[(rid + jb + 1) * KD]);
        const floatx4* k2 = reinterpret_cast<const floatx4*>(&ks[(rid + jb + 2) * KD]);
        const floatx4* k3 = reinterpret_cast<const floatx4*>(&ks[(rid + jb + 3) * KD]);
        floatx4 a0 = {0,0,0,0}, a1 = {0,0,0,0}, a2 = {0,0,0,0}, a3 = {0,0,0,0};
#pragma unroll
        for (int c = 0; c < 16; ++c) {
            floatx4 qv = qr[c];
            a0 += qv * k0[c];
            a1 += qv * k1[c];
            a2 += qv * k2[c];
            a3 += qv * k3[c];
        }
        float s0 = a0.x + a0.y + a0.z + a0.w;
        float s1 = a1.x + a1.y + a1.z + a1.w;
        float s2 = a2.x + a2.y + a2.z + a2.w;
        float s3 = a3.x + a3.y + a3.z + a3.w;
        const float* rp = rpb + h * 25 + pi;
        if (jb + 0 < NA_K) wgt[l][jb + 0] = s0 + rp[jb + 0];
        if (jb + 1 < NA_K) wgt[l][jb + 1] = s1 + rp[jb + 1];
        if (jb + 2 < NA_K) wgt[l][jb + 2] = s2 + rp[jb + 2];
        if (jb + 3 < NA_K) wgt[l][jb + 3] = s3 + rp[jb + 3];
    }
    __syncthreads();

    // ---- phase 3: softmax per l ----
    if (t < TL) {
        float m = -1e30f;
#pragma unroll
        for (int j = 0; j < NA_K; ++j) m = fmaxf(m, wgt[t][j]);
        float sum = 0.f;
#pragma unroll
        for (int j = 0; j < NA_K; ++j) {
            float e = expf(wgt[t][j] - m);
            wgt[t][j] = e;
            sum += e;
        }
        float inv = 1.f / sum;
#pragma unroll
        for (int j = 0; j < NA_K; ++j) wgt[t][j] *= inv;
    }
    __syncthreads();

    // ---- phase 4: AV. thread (l, 16-d chunk), float4 reads ----
    {
        const int l  = t & 63;
        const int d0 = (t >> 6) * 16;
        int ig = l0 + l;
        int ni = ig - 6;
        if (ni < 0) ni = 0;
        if (ni > NA_L - NA_K) ni = NA_L - NA_K;
        int rid = ni - rs;
        floatx4 o0 = {0,0,0,0}, o1 = {0,0,0,0}, o2 = {0,0,0,0}, o3 = {0,0,0,0};
#pragma unroll
        for (int j = 0; j < NA_K; ++j) {
            float w = wgt[l][j];
            const floatx4* vr = reinterpret_cast<const floatx4*>(&vs[(rid + j) * KD + d0]);
            o0 += w * vr[0];
            o1 += w * vr[1];
            o2 += w * vr[2];
            o3 += w * vr[3];
        }
        unsigned short* dst = qkv + (rowbase + ig) * 3072 + h * 64 + d0;
        uint4 p0, p1;
        p0.x = (unsigned int)f2bf(o0.x) | ((unsigned int)f2bf(o0.y) << 16);
        p0.y = (unsigned int)f2bf(o0.z) | ((unsigned int)f2bf(o0.w) << 16);
        p0.z = (unsigned int)f2bf(o1.x) | ((unsigned int)f2bf(o1.y) << 16);
        p0.w = (unsigned int)f2bf(o1.z) | ((unsigned int)f2bf(o1.w) << 16);
        p1.x = (unsigned int)f2bf(o2.x) | ((unsigned int)f2bf(o2.y) << 16);
        p1.y = (unsigned int)f2bf(o2.z) | ((unsigned int)f2bf(o2.w) << 16);
        p1.z = (unsigned int)f2bf(o3.x) | ((unsigned int)f2bf(o3.y) << 16);
        p1.w = (unsigned int)f2bf(o3.z) | ((unsigned int)f2bf(o3.w) << 16);
        *reinterpret_cast<uint4*>(dst)     = p0;
        *reinterpret_cast<uint4*>(dst + 8) = p1;
    }
}

// ---------------------------------------------------------------------------
extern "C" void kernel_launch(void* const* d_in, const int* in_sizes, int n_in,
                              void* d_out, int out_size, void* d_ws, size_t ws_size,
                              hipStream_t stream)
{
    const float* x      = (const float*)d_in[0];
    const float* w_qkv  = (const float*)d_in[1];
    const float* b_qkv  = (const float*)d_in[2];
    const float* rpb    = (const float*)d_in[3];
    const float* w_proj = (const float*)d_in[4];
    const float* b_proj = (const float*)d_in[5];
    float* out = (float*)d_out;

    const int M  = 4 * 4096;   // 16384
    const int K  = 1024;
    const int N1 = 3072;
    const int N2 = 1024;

    unsigned short* qkv = (unsigned short*)d_ws;              // 96 MiB
    unsigned short* Wt1 = qkv + (size_t)M * N1;               // 6 MiB
    unsigned short* Wt2 = Wt1 + (size_t)N1 * K;               // 2 MiB
    unsigned short* xb  = Wt2 + (size_t)N2 * K;               // 32 MiB
    size_t need_mid  = ((size_t)M * N1 + (size_t)N1 * K + (size_t)N2 * K) * 2;
    size_t need_fast = need_mid + (size_t)M * K * 2;

    const int na_grid = 4 * (NA_L / TL) * NA_H;               // 4096

    if (ws_size >= need_fast) {
        convert_f32_bf16<<<dim3(M * K / (256 * 8)), 256, 0, stream>>>(x, xb);
        transpose_f32_to_bf16<<<dim3(N1 / 32, K / 32), 256, 0, stream>>>(w_qkv, Wt1, K, N1);
        transpose_f32_to_bf16<<<dim3(N2 / 32, K / 32), 256, 0, stream>>>(w_proj, Wt2, K, N2);
        gemm_pipe_kernel<false><<<dim3(N1 / TBN, M / TBM), 512, 0, stream>>>(
            xb, Wt1, b_qkv, qkv, N1, K, K, N1);
        na1d_tiled_kernel<<<dim3(na_grid), 256, 0, stream>>>(qkv, rpb);
        gemm_pipe_kernel<true><<<dim3(N2 / TBN, M / TBM), 512, 0, stream>>>(
            qkv, Wt2, b_proj, out, N2, K, N1, N2);
    } else if (ws_size >= need_mid) {
        transpose_f32_to_bf16<<<dim3(N1 / 32, K / 32), 256, 0, stream>>>(w_qkv, Wt1, K, N1);
        transpose_f32_to_bf16<<<dim3(N2 / 32, K / 32), 256, 0, stream>>>(w_proj, Wt2, K, N2);
        gemm_bias_kernel<true, false, true><<<dim3(N1 / BN, M / BM), 256, 0, stream>>>(
            x, Wt1, b_qkv, qkv, N1, K, K, N1);
        na1d_tiled_kernel<<<dim3(na_grid), 256, 0, stream>>>(qkv, rpb);
        gemm_bias_kernel<false, true, true><<<dim3(N2 / BN, M / BM), 256, 0, stream>>>(
            qkv, Wt2, b_proj, out, N2, K, N1, N2);
    } else {
        gemm_bias_kernel<true, false, false><<<dim3(N1 / BN, M / BM), 256, 0, stream>>>(
            x, w_qkv, b_qkv, qkv, N1, K, K, N1);
        na1d_tiled_kernel<<<dim3(na_grid), 256, 0, stream>>>(qkv, rpb);
        gemm_bias_kernel<false, true, false><<<dim3(N2 / BN, M / BM), 256, 0, stream>>>(
            qkv, w_proj, b_proj, out, N2, K, N1, N2);
    }
}

// Round 3
// 366.283 us; speedup vs baseline: 1.1529x; 1.0539x over previous
//
#include <hip/hip_runtime.h>

typedef __bf16 bf16x8_t __attribute__((ext_vector_type(8)));
typedef float  f32x4_t  __attribute__((ext_vector_type(4)));
typedef float  floatx4  __attribute__((ext_vector_type(4)));
typedef unsigned short ushortx4 __attribute__((ext_vector_type(4)));

__device__ __forceinline__ float bf2f(unsigned short u) {
    union { unsigned int i; float f; } c; c.i = ((unsigned int)u) << 16; return c.f;
}
__device__ __forceinline__ unsigned short f2bf(float f) {
    union { float f; unsigned int i; } c; c.f = f;
    unsigned int u = c.i;
    u += 0x7fffu + ((u >> 16) & 1u);   // RNE
    return (unsigned short)(u >> 16);
}
__device__ __forceinline__ void unpack8(uint4 u, float* dst, float sc) {
    dst[0] = bf2f((unsigned short)(u.x & 0xffff)) * sc;
    dst[1] = bf2f((unsigned short)(u.x >> 16)) * sc;
    dst[2] = bf2f((unsigned short)(u.y & 0xffff)) * sc;
    dst[3] = bf2f((unsigned short)(u.y >> 16)) * sc;
    dst[4] = bf2f((unsigned short)(u.z & 0xffff)) * sc;
    dst[5] = bf2f((unsigned short)(u.z >> 16)) * sc;
    dst[6] = bf2f((unsigned short)(u.w & 0xffff)) * sc;
    dst[7] = bf2f((unsigned short)(u.w >> 16)) * sc;
}

// async global->LDS, 16 B per lane; lds dest = wave-uniform base + lane*16
__device__ __forceinline__ void load_lds16(const unsigned short* g, unsigned short* l) {
    __builtin_amdgcn_global_load_lds(
        (const __attribute__((address_space(1))) unsigned int*)g,
        (__attribute__((address_space(3))) unsigned int*)l, 16, 0, 0);
}

// ---------------------------------------------------------------------------
// x (f32) -> bf16, 8 elems/thread
// ---------------------------------------------------------------------------
__global__ __launch_bounds__(256) void convert_f32_bf16(
    const float* __restrict__ x, unsigned short* __restrict__ xb)
{
    size_t i = ((size_t)blockIdx.x * 256 + threadIdx.x) * 8;
    floatx4 a = *reinterpret_cast<const floatx4*>(x + i);
    floatx4 b = *reinterpret_cast<const floatx4*>(x + i + 4);
    uint4 o;
    o.x = (unsigned int)f2bf(a.x) | ((unsigned int)f2bf(a.y) << 16);
    o.y = (unsigned int)f2bf(a.z) | ((unsigned int)f2bf(a.w) << 16);
    o.z = (unsigned int)f2bf(b.x) | ((unsigned int)f2bf(b.y) << 16);
    o.w = (unsigned int)f2bf(b.z) | ((unsigned int)f2bf(b.w) << 16);
    *reinterpret_cast<uint4*>(xb + i) = o;
}

// ---------------------------------------------------------------------------
// Weight prep: Wt[n][k] (bf16) = W[k][n] (f32). 32x32 LDS-tiled transpose.
// ---------------------------------------------------------------------------
__global__ __launch_bounds__(256) void transpose_f32_to_bf16(
    const float* __restrict__ W, unsigned short* __restrict__ Wt,
    int Kdim, int Ndim)
{
    __shared__ float tile[32][33];
    const int n0 = blockIdx.x * 32, k0 = blockIdx.y * 32;
    const int tx = threadIdx.x & 31, ty = threadIdx.x >> 5;   // ty 0..7
#pragma unroll
    for (int r = 0; r < 4; ++r) {
        int k = ty + r * 8;
        tile[k][tx] = W[(size_t)(k0 + k) * Ndim + n0 + tx];
    }
    __syncthreads();
#pragma unroll
    for (int r = 0; r < 4; ++r) {
        int n = ty + r * 8;
        Wt[(size_t)(n0 + n) * Kdim + k0 + tx] = f2bf(tile[tx][n]);
    }
}

// ---------------------------------------------------------------------------
// 256x256-tile, 8-wave (2Mx4N), BK=32, 4-deep counted-vmcnt ring. v3:
//  - ONE barrier per K-tile (was 3): stages + 12 ds_reads + 32 MFMAs in one
//    window. Compiler emits progressive lgkmcnt(N) so MFMAs start as frags
//    land; waves desync inside the window -> one wave's LDS reads overlap
//    another wave's MFMAs (cross-wave pipe overlap the phase-locked version
//    never had). 32 MFMA per barrier.
//  - ring: iter t stages tile t+3 into buf (t+3)&3 = (t-1)&3 (readers of that
//    buf crossed barrier t-1 -> t before those stages issue). vmcnt(8) at
//    tile boundary (drains tile t+1's 4 loads, issued ~2 tiles ago); tail
//    4 -> 0. Never drain 0 mid-loop (T4).
//  - XOR swizzle identical to R6-proven (0 bank conflicts measured).
//  - XCD-aware bijective blockIdx swizzle (T1), grid %8==0 both call sites.
//  - bf16 epilogue: per-wave LDS repack (16KB slice of the freed ring,
//    XOR-chunk swizzle) -> dwordx4 stores, full 64B lines (kills the 1.85x
//    write amplification seen in R2: WRITE_SIZE 186MB vs 100MB ideal).
// Requires: M%256==0, N%256==0, K%32==0, K>=128, grid %8==0.
// ---------------------------------------------------------------------------
#define TBM 256
#define TBN 256
#define TBK 32

template<bool C_F32>
__global__ __launch_bounds__(512, 2) void gemm_pipe_kernel(
    const unsigned short* __restrict__ A, const unsigned short* __restrict__ Wt,
    const float* __restrict__ bias, void* __restrict__ Cp,
    int N, int K, int lda, int ldc)
{
    // one contiguous 128 KiB block: A bufs = SMEM[0..3], B bufs = SMEM[4..7]
    __shared__ __align__(16) unsigned short SMEM[8][8192];

    const int tid  = threadIdx.x;
    const int lane = tid & 63;
    const int wid  = tid >> 6;        // 0..7
    const int wm   = wid >> 2;        // 0..1  (M half: 128 rows)
    const int wn   = wid & 3;         // 0..3  (N quarter: 64 cols)
    const int quad = lane >> 4;       // 0..3
    const int lr   = lane & 15;       // 0..15

    // XCD-aware bijective swizzle (nwg % 8 == 0 at both call sites)
    const int gx  = gridDim.x;
    const int cpx = (gx * gridDim.y) >> 3;
    const int bid = blockIdx.y * gx + blockIdx.x;
    const int nid = (bid & 7) * cpx + (bid >> 3);
    const int m0 = (nid / gx) * TBM;
    const int n0 = (nid % gx) * TBN;

    const int s_row = tid >> 2;                                  // 0..127
    const int c_sw  = ((tid & 3) ^ ((tid >> 3) & 3)) * 8;        // swizzled source chunk
    const int xq    = (quad ^ ((lr >> 1) & 3)) * 8;              // swizzled read chunk
    const int NT    = K >> 5;

    const unsigned short* Ag  = A  + (size_t)(m0 + s_row) * lda + c_sw;
    const unsigned short* Ag2 = Ag + (size_t)128 * lda;
    const unsigned short* Bg  = Wt + (size_t)(n0 + s_row) * K + c_sw;
    const unsigned short* Bg2 = Bg + (size_t)128 * K;

    f32x4_t acc[8][4];
#pragma unroll
    for (int i = 0; i < 8; ++i)
#pragma unroll
        for (int j = 0; j < 4; ++j)
            acc[i][j] = (f32x4_t){0.f, 0.f, 0.f, 0.f};

    // ---- prologue: stage tiles 0,1,2 (12 issues/wave), wait tile 0 ----
#pragma unroll
    for (int tt = 0; tt < 3; ++tt) {
        load_lds16(Ag  + tt * TBK, &SMEM[tt][wid * 512]);
        load_lds16(Ag2 + tt * TBK, &SMEM[tt][4096 + wid * 512]);
        load_lds16(Bg  + tt * TBK, &SMEM[4 + tt][wid * 512]);
        load_lds16(Bg2 + tt * TBK, &SMEM[4 + tt][4096 + wid * 512]);
    }
    asm volatile("s_waitcnt vmcnt(8)" ::: "memory");   // tile 0 landed (own slice)
    __builtin_amdgcn_s_barrier();                      // -> all waves' slices landed

    for (int tt = 0; tt < NT; ++tt) {
        const int b = tt & 3;
        const unsigned short* pa = &SMEM[b][0];
        const unsigned short* pb = &SMEM[4 + b][0];
        const bool st = (tt + 3) < NT;
        const int  sb = (tt + 3) & 3;
        const int  ko = (tt + 3) * TBK;

        // stages first (longest latency, independent)
        if (st) {
            load_lds16(Ag  + ko, &SMEM[sb][wid * 512]);
            load_lds16(Ag2 + ko, &SMEM[sb][4096 + wid * 512]);
            load_lds16(Bg  + ko, &SMEM[4 + sb][wid * 512]);
            load_lds16(Bg2 + ko, &SMEM[4 + sb][4096 + wid * 512]);
        }

        // all fragment reads; compiler interleaves lgkmcnt(N) with MFMAs
        bf16x8_t bv[4], av[8];
#pragma unroll
        for (int j = 0; j < 4; ++j)
            bv[j] = *reinterpret_cast<const bf16x8_t*>(pb + (wn * 64 + j * 16 + lr) * TBK + xq);
#pragma unroll
        for (int i = 0; i < 8; ++i)
            av[i] = *reinterpret_cast<const bf16x8_t*>(pa + (wm * 128 + i * 16 + lr) * TBK + xq);

        __builtin_amdgcn_s_setprio(1);
#pragma unroll
        for (int i = 0; i < 8; ++i)
#pragma unroll
            for (int j = 0; j < 4; ++j)
                acc[i][j] = __builtin_amdgcn_mfma_f32_16x16x32_bf16(av[i], bv[j], acc[i][j], 0, 0, 0);
        __builtin_amdgcn_s_setprio(0);

        // tile boundary: counted drain, never 0 mid-loop (T4)
        if (tt < NT - 3)       asm volatile("s_waitcnt vmcnt(8)" ::: "memory");
        else if (tt == NT - 3) asm volatile("s_waitcnt vmcnt(4)" ::: "memory");
        else                   asm volatile("s_waitcnt vmcnt(0)" ::: "memory");
        __builtin_amdgcn_s_barrier();
    }

    // ---- epilogue ----
    if (C_F32) {
        // f32 stores: lanes 0..15 cover 64B lines already -> direct
#pragma unroll
        for (int j = 0; j < 4; ++j) {
            int col = n0 + wn * 64 + j * 16 + lr;
            float bj = bias[col];
#pragma unroll
            for (int i = 0; i < 8; ++i) {
                int rbase = m0 + wm * 128 + i * 16 + quad * 4;
#pragma unroll
                for (int r = 0; r < 4; ++r) {
                    float v = acc[i][j][r] + bj;
                    ((float*)Cp)[(size_t)(rbase + r) * ldc + col] = v;
                }
            }
        }
    } else {
        // bf16: repack through the wave's private 16KB LDS slice (ring is
        // dead after final barrier), XOR-chunk swizzle, then dwordx4 stores.
        unsigned short* ep = &SMEM[wid][0];            // [128][64] shorts
#pragma unroll
        for (int j = 0; j < 4; ++j) {
            float bj = bias[n0 + wn * 64 + j * 16 + lr];
#pragma unroll
            for (int i = 0; i < 8; ++i) {
#pragma unroll
                for (int r = 0; r < 4; ++r) {
                    int row = i * 16 + quad * 4 + r;           // 0..127
                    int col = j * 16 + lr;                     // 0..63
                    int ch  = (col >> 3) ^ (row & 7);
                    ep[row * 64 + ch * 8 + (col & 7)] = f2bf(acc[i][j][r] + bj);
                }
            }
        }
        // wave-private slice: lgkmcnt ordering suffices (compiler-tracked)
        unsigned short* Cb = (unsigned short*)Cp;
        const int cch = lane & 7;
#pragma unroll
        for (int s = 0; s < 16; ++s) {
            int row = s * 8 + (lane >> 3);                     // 0..127
            int ch  = cch ^ (row & 7);
            uint4 v = *reinterpret_cast<const uint4*>(&ep[row * 64 + ch * 8]);
            *reinterpret_cast<uint4*>(
                Cb + (size_t)(m0 + wm * 128 + row) * ldc + n0 + wn * 64 + cch * 8) = v;
        }
    }
}

// ---------------------------------------------------------------------------
// Fallback GEMM (R3/R4-proven): padded LDS, regular staging.
// ---------------------------------------------------------------------------
#define BM 128
#define BN 128
#define BK 32
#define LDT 40

template<bool A_F32, bool C_F32, bool BT>
__global__ __launch_bounds__(256) void gemm_bias_kernel(
    const void* __restrict__ Ap, const void* __restrict__ Wp,
    const float* __restrict__ bias, void* __restrict__ Cp,
    int N, int K, int lda, int ldc)
{
    __shared__ __align__(16) unsigned short As[BM * LDT];
    __shared__ __align__(16) unsigned short Bs[BN * LDT];

    const int tid  = threadIdx.x;
    const int lane = tid & 63;
    const int wid  = tid >> 6;
    const int wm   = wid >> 1;
    const int wn   = wid & 1;
    const int quad = lane >> 4;
    const int lr   = lane & 15;

    const int m0 = blockIdx.y * BM;
    const int n0 = blockIdx.x * BN;

    f32x4_t acc[4][4];
#pragma unroll
    for (int i = 0; i < 4; ++i)
#pragma unroll
        for (int j = 0; j < 4; ++j)
            acc[i][j] = (f32x4_t){0.f, 0.f, 0.f, 0.f};

    for (int k0 = 0; k0 < K; k0 += BK) {
        if (A_F32) {
            const float* A = (const float*)Ap;
#pragma unroll
            for (int it = 0; it < 4; ++it) {
                int q   = tid + it * 256;
                int row = q >> 3;
                int col = (q & 7) * 4;
                floatx4 f = *reinterpret_cast<const floatx4*>(A + (size_t)(m0 + row) * lda + k0 + col);
                ushortx4 s;
                s.x = f2bf(f.x); s.y = f2bf(f.y); s.z = f2bf(f.z); s.w = f2bf(f.w);
                *reinterpret_cast<ushortx4*>(&As[row * LDT + col]) = s;
            }
        } else {
            const unsigned short* A = (const unsigned short*)Ap;
            int a_row = tid >> 2;
            int a_col = (tid & 3) * 8;
#pragma unroll
            for (int r = 0; r < 2; ++r) {
                int row = a_row + r * 64;
                uint4 u = *reinterpret_cast<const uint4*>(A + (size_t)(m0 + row) * lda + k0 + a_col);
                *reinterpret_cast<uint4*>(&As[row * LDT + a_col]) = u;
            }
        }
        if (BT) {
            const unsigned short* Wt = (const unsigned short*)Wp;
            int b_row = tid >> 2;
            int b_col = (tid & 3) * 8;
#pragma unroll
            for (int r = 0; r < 2; ++r) {
                int n = b_row + r * 64;
                uint4 u = *reinterpret_cast<const uint4*>(Wt + (size_t)(n0 + n) * K + k0 + b_col);
                *reinterpret_cast<uint4*>(&Bs[n * LDT + b_col]) = u;
            }
        } else {
            const float* W = (const float*)Wp;
#pragma unroll
            for (int it = 0; it < 4; ++it) {
                int q  = tid + it * 256;
                int kk = q >> 5;
                int nn = (q & 31) * 4;
                floatx4 f = *reinterpret_cast<const floatx4*>(W + (size_t)(k0 + kk) * N + n0 + nn);
                Bs[(nn + 0) * LDT + kk] = f2bf(f.x);
                Bs[(nn + 1) * LDT + kk] = f2bf(f.y);
                Bs[(nn + 2) * LDT + kk] = f2bf(f.z);
                Bs[(nn + 3) * LDT + kk] = f2bf(f.w);
            }
        }
        __syncthreads();

        bf16x8_t av[4], bv[4];
#pragma unroll
        for (int i = 0; i < 4; ++i)
            av[i] = *reinterpret_cast<const bf16x8_t*>(&As[(wm * 64 + i * 16 + lr) * LDT + quad * 8]);
#pragma unroll
        for (int j = 0; j < 4; ++j)
            bv[j] = *reinterpret_cast<const bf16x8_t*>(&Bs[(wn * 64 + j * 16 + lr) * LDT + quad * 8]);

#pragma unroll
        for (int i = 0; i < 4; ++i)
#pragma unroll
            for (int j = 0; j < 4; ++j)
                acc[i][j] = __builtin_amdgcn_mfma_f32_16x16x32_bf16(av[i], bv[j], acc[i][j], 0, 0, 0);

        __syncthreads();
    }

#pragma unroll
    for (int j = 0; j < 4; ++j) {
        int col = n0 + wn * 64 + j * 16 + lr;
        float bj = bias[col];
#pragma unroll
        for (int i = 0; i < 4; ++i) {
            int rbase = m0 + wm * 64 + i * 16 + quad * 4;
#pragma unroll
            for (int r = 0; r < 4; ++r) {
                float v = acc[i][j][r] + bj;
                size_t idx = (size_t)(rbase + r) * ldc + col;
                if (C_F32) ((float*)Cp)[idx] = v;
                else       ((unsigned short*)Cp)[idx] = f2bf(v);
            }
        }
    }
}

// ---------------------------------------------------------------------------
// Tiled neighborhood attention v2 (unchanged this round; R6-verified).
// ---------------------------------------------------------------------------
#define NA_L 4096
#define NA_K 13
#define NA_H 16
#define NA_D 64
#define NA_SCALE 0.125f
#define TL  64
#define WIN 76          // TL + 12
#define KD  68          // padded f32 row (17 float4 chunks)

__global__ __launch_bounds__(256) void na1d_tiled_kernel(
    unsigned short* qkv, const float* __restrict__ rpb)
{
    __shared__ __align__(16) float ks[WIN * KD];
    __shared__ __align__(16) float vs[WIN * KD];
    __shared__ __align__(16) float qs[TL * KD];
    __shared__ float wgt[TL][NA_K];

    const int bid = blockIdx.x;
    const int h  = bid & 15;
    const int lt = (bid >> 4) & 63;
    const int b  = bid >> 10;
    const int l0 = lt * TL;
    const int rs = l0 - 6;

    const int t = threadIdx.x;
    const size_t rowbase = (size_t)b * NA_L;

    // ---- phase 1: prefetch q + k/v window, then unpack to LDS ----
    {
        const int qr = t >> 2;
        const int qc = (t & 3) * 16;
        const unsigned short* qsrc = qkv + (rowbase + l0 + qr) * 3072 + h * 64 + qc;
        uint4 q0 = *reinterpret_cast<const uint4*>(qsrc);
        uint4 q1 = *reinterpret_cast<const uint4*>(qsrc + 8);

        const int r0 = t >> 3;            // 0..31
        const int cc = (t & 7) * 8;
        int g0 = rs + r0;      g0 = g0 < 0 ? 0 : (g0 > NA_L - 1 ? NA_L - 1 : g0);
        int g1 = rs + r0 + 32; g1 = g1 < 0 ? 0 : (g1 > NA_L - 1 ? NA_L - 1 : g1);
        const unsigned short* p0 = qkv + (rowbase + g0) * 3072 + 1024 + h * 64 + cc;
        const unsigned short* p1 = qkv + (rowbase + g1) * 3072 + 1024 + h * 64 + cc;
        uint4 k0 = *reinterpret_cast<const uint4*>(p0);
        uint4 v0 = *reinterpret_cast<const uint4*>(p0 + 1024);
        uint4 k1 = *reinterpret_cast<const uint4*>(p1);
        uint4 v1 = *reinterpret_cast<const uint4*>(p1 + 1024);
        uint4 k2, v2;
        if (t < 96) {
            int g2 = rs + r0 + 64; g2 = g2 < 0 ? 0 : (g2 > NA_L - 1 ? NA_L - 1 : g2);
            const unsigned short* p2 = qkv + (rowbase + g2) * 3072 + 1024 + h * 64 + cc;
            k2 = *reinterpret_cast<const uint4*>(p2);
            v2 = *reinterpret_cast<const uint4*>(p2 + 1024);
        }

        unpack8(q0, &qs[qr * KD + qc], NA_SCALE);
        unpack8(q1, &qs[qr * KD + qc + 8], NA_SCALE);
        unpack8(k0, &ks[r0 * KD + cc], 1.f);
        unpack8(v0, &vs[r0 * KD + cc], 1.f);
        unpack8(k1, &ks[(r0 + 32) * KD + cc], 1.f);
        unpack8(v1, &vs[(r0 + 32) * KD + cc], 1.f);
        if (t < 96) {
            unpack8(k2, &ks[(r0 + 64) * KD + cc], 1.f);
            unpack8(v2, &vs[(r0 + 64) * KD + cc], 1.f);
        }
    }
    __syncthreads();

    // ---- phase 2: logits; wave jb handles j = 4jb..4jb+3 for lane's l ----
    {
        const int l  = t & 63;
        const int jb = (t >> 6) * 4;
        int ig = l0 + l;
        int ni = ig - 6;
        if (ni < 0) ni = 0;
        if (ni > NA_L - NA_K) ni = NA_L - NA_K;
        int rid = ni - rs;                    // 0..57
        int pi  = ni - ig + 12;
        const floatx4* qr = reinterpret_cast<const floatx4*>(&qs[l * KD]);
        const floatx4* k0 = reinterpret_cast<const floatx4*>(&ks[(rid + jb + 0) * KD]);
        const floatx4* k1 = reinterpret_cast<const floatx4*>(&ks[(rid + jb + 1) * KD]);
        const floatx4* k2 = reinterpret_cast<const floatx4*>(&ks[(rid + jb + 2) * KD]);
        const floatx4* k3 = reinterpret_cast<const floatx4*>(&ks[(rid + jb + 3) * KD]);
        floatx4 a0 = {0,0,0,0}, a1 = {0,0,0,0}, a2 = {0,0,0,0}, a3 = {0,0,0,0};
#pragma unroll
        for (int c = 0; c < 16; ++c) {
            floatx4 qv = qr[c];
            a0 += qv * k0[c];
            a1 += qv * k1[c];
            a2 += qv * k2[c];
            a3 += qv * k3[c];
        }
        float s0 = a0.x + a0.y + a0.z + a0.w;
        float s1 = a1.x + a1.y + a1.z + a1.w;
        float s2 = a2.x + a2.y + a2.z + a2.w;
        float s3 = a3.x + a3.y + a3.z + a3.w;
        const float* rp = rpb + h * 25 + pi;
        if (jb + 0 < NA_K) wgt[l][jb + 0] = s0 + rp[jb + 0];
        if (jb + 1 < NA_K) wgt[l][jb + 1] = s1 + rp[jb + 1];
        if (jb + 2 < NA_K) wgt[l][jb + 2] = s2 + rp[jb + 2];
        if (jb + 3 < NA_K) wgt[l][jb + 3] = s3 + rp[jb + 3];
    }
    __syncthreads();

    // ---- phase 3: softmax per l ----
    if (t < TL) {
        float m = -1e30f;
#pragma unroll
        for (int j = 0; j < NA_K; ++j) m = fmaxf(m, wgt[t][j]);
        float sum = 0.f;
#pragma unroll
        for (int j = 0; j < NA_K; ++j) {
            float e = expf(wgt[t][j] - m);
            wgt[t][j] = e;
            sum += e;
        }
        float inv = 1.f / sum;
#pragma unroll
        for (int j = 0; j < NA_K; ++j) wgt[t][j] *= inv;
    }
    __syncthreads();

    // ---- phase 4: AV. thread (l, 16-d chunk), float4 reads ----
    {
        const int l  = t & 63;
        const int d0 = (t >> 6) * 16;
        int ig = l0 + l;
        int ni = ig - 6;
        if (ni < 0) ni = 0;
        if (ni > NA_L - NA_K) ni = NA_L - NA_K;
        int rid = ni - rs;
        floatx4 o0 = {0,0,0,0}, o1 = {0,0,0,0}, o2 = {0,0,0,0}, o3 = {0,0,0,0};
#pragma unroll
        for (int j = 0; j < NA_K; ++j) {
            float w = wgt[l][j];
            const floatx4* vr = reinterpret_cast<const floatx4*>(&vs[(rid + j) * KD + d0]);
            o0 += w * vr[0];
            o1 += w * vr[1];
            o2 += w * vr[2];
            o3 += w * vr[3];
        }
        unsigned short* dst = qkv + (rowbase + ig) * 3072 + h * 64 + d0;
        uint4 p0, p1;
        p0.x = (unsigned int)f2bf(o0.x) | ((unsigned int)f2bf(o0.y) << 16);
        p0.y = (unsigned int)f2bf(o0.z) | ((unsigned int)f2bf(o0.w) << 16);
        p0.z = (unsigned int)f2bf(o1.x) | ((unsigned int)f2bf(o1.y) << 16);
        p0.w = (unsigned int)f2bf(o1.z) | ((unsigned int)f2bf(o1.w) << 16);
        p1.x = (unsigned int)f2bf(o2.x) | ((unsigned int)f2bf(o2.y) << 16);
        p1.y = (unsigned int)f2bf(o2.z) | ((unsigned int)f2bf(o2.w) << 16);
        p1.z = (unsigned int)f2bf(o3.x) | ((unsigned int)f2bf(o3.y) << 16);
        p1.w = (unsigned int)f2bf(o3.z) | ((unsigned int)f2bf(o3.w) << 16);
        *reinterpret_cast<uint4*>(dst)     = p0;
        *reinterpret_cast<uint4*>(dst + 8) = p1;
    }
}

// ---------------------------------------------------------------------------
extern "C" void kernel_launch(void* const* d_in, const int* in_sizes, int n_in,
                              void* d_out, int out_size, void* d_ws, size_t ws_size,
                              hipStream_t stream)
{
    const float* x      = (const float*)d_in[0];
    const float* w_qkv  = (const float*)d_in[1];
    const float* b_qkv  = (const float*)d_in[2];
    const float* rpb    = (const float*)d_in[3];
    const float* w_proj = (const float*)d_in[4];
    const float* b_proj = (const float*)d_in[5];
    float* out = (float*)d_out;

    const int M  = 4 * 4096;   // 16384
    const int K  = 1024;
    const int N1 = 3072;
    const int N2 = 1024;

    unsigned short* qkv = (unsigned short*)d_ws;              // 96 MiB
    unsigned short* Wt1 = qkv + (size_t)M * N1;               // 6 MiB
    unsigned short* Wt2 = Wt1 + (size_t)N1 * K;               // 2 MiB
    unsigned short* xb  = Wt2 + (size_t)N2 * K;               // 32 MiB
    size_t need_mid  = ((size_t)M * N1 + (size_t)N1 * K + (size_t)N2 * K) * 2;
    size_t need_fast = need_mid + (size_t)M * K * 2;

    const int na_grid = 4 * (NA_L / TL) * NA_H;               // 4096

    if (ws_size >= need_fast) {
        convert_f32_bf16<<<dim3(M * K / (256 * 8)), 256, 0, stream>>>(x, xb);
        transpose_f32_to_bf16<<<dim3(N1 / 32, K / 32), 256, 0, stream>>>(w_qkv, Wt1, K, N1);
        transpose_f32_to_bf16<<<dim3(N2 / 32, K / 32), 256, 0, stream>>>(w_proj, Wt2, K, N2);
        gemm_pipe_kernel<false><<<dim3(N1 / TBN, M / TBM), 512, 0, stream>>>(
            xb, Wt1, b_qkv, qkv, N1, K, K, N1);
        na1d_tiled_kernel<<<dim3(na_grid), 256, 0, stream>>>(qkv, rpb);
        gemm_pipe_kernel<true><<<dim3(N2 / TBN, M / TBM), 512, 0, stream>>>(
            qkv, Wt2, b_proj, out, N2, K, N1, N2);
    } else if (ws_size >= need_mid) {
        transpose_f32_to_bf16<<<dim3(N1 / 32, K / 32), 256, 0, stream>>>(w_qkv, Wt1, K, N1);
        transpose_f32_to_bf16<<<dim3(N2 / 32, K / 32), 256, 0, stream>>>(w_proj, Wt2, K, N2);
        gemm_bias_kernel<true, false, true><<<dim3(N1 / BN, M / BM), 256, 0, stream>>>(
            x, Wt1, b_qkv, qkv, N1, K, K, N1);
        na1d_tiled_kernel<<<dim3(na_grid), 256, 0, stream>>>(qkv, rpb);
        gemm_bias_kernel<false, true, true><<<dim3(N2 / BN, M / BM), 256, 0, stream>>>(
            qkv, Wt2, b_proj, out, N2, K, N1, N2);
    } else {
        gemm_bias_kernel<true, false, false><<<dim3(N1 / BN, M / BM), 256, 0, stream>>>(
            x, w_qkv, b_qkv, qkv, N1, K, K, N1);
        na1d_tiled_kernel<<<dim3(na_grid), 256, 0, stream>>>(qkv, rpb);
        gemm_bias_kernel<false, true, false><<<dim3(N2 / BN, M / BM), 256, 0, stream>>>(
            qkv, w_proj, b_proj, out, N2, K, N1, N2);
    }
}

// Round 4
// 347.447 us; speedup vs baseline: 1.2154x; 1.0542x over previous
//
#include <hip/hip_runtime.h>

typedef __bf16 bf16x8_t __attribute__((ext_vector_type(8)));
typedef float  f32x4_t  __attribute__((ext_vector_type(4)));
typedef float  floatx4  __attribute__((ext_vector_type(4)));
typedef unsigned short ushortx4 __attribute__((ext_vector_type(4)));

__device__ __forceinline__ float bf2f(unsigned short u) {
    union { unsigned int i; float f; } c; c.i = ((unsigned int)u) << 16; return c.f;
}
__device__ __forceinline__ unsigned short f2bf(float f) {
    union { float f; unsigned int i; } c; c.f = f;
    unsigned int u = c.i;
    u += 0x7fffu + ((u >> 16) & 1u);   // RNE
    return (unsigned short)(u >> 16);
}
// 8 packed bf16 (as uint4) -> 2 float4, pure bit ops (1 VALU op/elem)
__device__ __forceinline__ void cvt8(uint4 u, floatx4& lo, floatx4& hi) {
    union { unsigned int i; float f; } c;
    c.i = u.x << 16;          lo.x = c.f;
    c.i = u.x & 0xffff0000u;  lo.y = c.f;
    c.i = u.y << 16;          lo.z = c.f;
    c.i = u.y & 0xffff0000u;  lo.w = c.f;
    c.i = u.z << 16;          hi.x = c.f;
    c.i = u.z & 0xffff0000u;  hi.y = c.f;
    c.i = u.w << 16;          hi.z = c.f;
    c.i = u.w & 0xffff0000u;  hi.w = c.f;
}

// async global->LDS, 16 B per lane; lds dest = wave-uniform base + lane*16
__device__ __forceinline__ void load_lds16(const unsigned short* g, unsigned short* l) {
    __builtin_amdgcn_global_load_lds(
        (const __attribute__((address_space(1))) unsigned int*)g,
        (__attribute__((address_space(3))) unsigned int*)l, 16, 0, 0);
}

// ---------------------------------------------------------------------------
// x (f32) -> bf16, 8 elems/thread
// ---------------------------------------------------------------------------
__global__ __launch_bounds__(256) void convert_f32_bf16(
    const float* __restrict__ x, unsigned short* __restrict__ xb)
{
    size_t i = ((size_t)blockIdx.x * 256 + threadIdx.x) * 8;
    floatx4 a = *reinterpret_cast<const floatx4*>(x + i);
    floatx4 b = *reinterpret_cast<const floatx4*>(x + i + 4);
    uint4 o;
    o.x = (unsigned int)f2bf(a.x) | ((unsigned int)f2bf(a.y) << 16);
    o.y = (unsigned int)f2bf(a.z) | ((unsigned int)f2bf(a.w) << 16);
    o.z = (unsigned int)f2bf(b.x) | ((unsigned int)f2bf(b.y) << 16);
    o.w = (unsigned int)f2bf(b.z) | ((unsigned int)f2bf(b.w) << 16);
    *reinterpret_cast<uint4*>(xb + i) = o;
}

// ---------------------------------------------------------------------------
// Weight prep: Wt[n][k] (bf16) = W[k][n] (f32). 32x32 LDS-tiled transpose.
// ---------------------------------------------------------------------------
__global__ __launch_bounds__(256) void transpose_f32_to_bf16(
    const float* __restrict__ W, unsigned short* __restrict__ Wt,
    int Kdim, int Ndim)
{
    __shared__ float tile[32][33];
    const int n0 = blockIdx.x * 32, k0 = blockIdx.y * 32;
    const int tx = threadIdx.x & 31, ty = threadIdx.x >> 5;   // ty 0..7
#pragma unroll
    for (int r = 0; r < 4; ++r) {
        int k = ty + r * 8;
        tile[k][tx] = W[(size_t)(k0 + k) * Ndim + n0 + tx];
    }
    __syncthreads();
#pragma unroll
    for (int r = 0; r < 4; ++r) {
        int n = ty + r * 8;
        Wt[(size_t)(n0 + n) * Kdim + k0 + tx] = f2bf(tile[tx][n]);
    }
}

// ---------------------------------------------------------------------------
// 256x256-tile, 8-wave (2Mx4N), BK=32, 4-deep counted-vmcnt ring. v3
// (unchanged from R3 — verified: MfmaUtil 37%, 0 bank conflicts, WRITE 98MB).
// ---------------------------------------------------------------------------
#define TBM 256
#define TBN 256
#define TBK 32

template<bool C_F32>
__global__ __launch_bounds__(512, 2) void gemm_pipe_kernel(
    const unsigned short* __restrict__ A, const unsigned short* __restrict__ Wt,
    const float* __restrict__ bias, void* __restrict__ Cp,
    int N, int K, int lda, int ldc)
{
    // one contiguous 128 KiB block: A bufs = SMEM[0..3], B bufs = SMEM[4..7]
    __shared__ __align__(16) unsigned short SMEM[8][8192];

    const int tid  = threadIdx.x;
    const int lane = tid & 63;
    const int wid  = tid >> 6;        // 0..7
    const int wm   = wid >> 2;        // 0..1  (M half: 128 rows)
    const int wn   = wid & 3;         // 0..3  (N quarter: 64 cols)
    const int quad = lane >> 4;       // 0..3
    const int lr   = lane & 15;       // 0..15

    // XCD-aware bijective swizzle (nwg % 8 == 0 at both call sites)
    const int gx  = gridDim.x;
    const int cpx = (gx * gridDim.y) >> 3;
    const int bid = blockIdx.y * gx + blockIdx.x;
    const int nid = (bid & 7) * cpx + (bid >> 3);
    const int m0 = (nid / gx) * TBM;
    const int n0 = (nid % gx) * TBN;

    const int s_row = tid >> 2;                                  // 0..127
    const int c_sw  = ((tid & 3) ^ ((tid >> 3) & 3)) * 8;        // swizzled source chunk
    const int xq    = (quad ^ ((lr >> 1) & 3)) * 8;              // swizzled read chunk
    const int NT    = K >> 5;

    const unsigned short* Ag  = A  + (size_t)(m0 + s_row) * lda + c_sw;
    const unsigned short* Ag2 = Ag + (size_t)128 * lda;
    const unsigned short* Bg  = Wt + (size_t)(n0 + s_row) * K + c_sw;
    const unsigned short* Bg2 = Bg + (size_t)128 * K;

    f32x4_t acc[8][4];
#pragma unroll
    for (int i = 0; i < 8; ++i)
#pragma unroll
        for (int j = 0; j < 4; ++j)
            acc[i][j] = (f32x4_t){0.f, 0.f, 0.f, 0.f};

    // ---- prologue: stage tiles 0,1,2 (12 issues/wave), wait tile 0 ----
#pragma unroll
    for (int tt = 0; tt < 3; ++tt) {
        load_lds16(Ag  + tt * TBK, &SMEM[tt][wid * 512]);
        load_lds16(Ag2 + tt * TBK, &SMEM[tt][4096 + wid * 512]);
        load_lds16(Bg  + tt * TBK, &SMEM[4 + tt][wid * 512]);
        load_lds16(Bg2 + tt * TBK, &SMEM[4 + tt][4096 + wid * 512]);
    }
    asm volatile("s_waitcnt vmcnt(8)" ::: "memory");   // tile 0 landed (own slice)
    __builtin_amdgcn_s_barrier();                      // -> all waves' slices landed

    for (int tt = 0; tt < NT; ++tt) {
        const int b = tt & 3;
        const unsigned short* pa = &SMEM[b][0];
        const unsigned short* pb = &SMEM[4 + b][0];
        const bool st = (tt + 3) < NT;
        const int  sb = (tt + 3) & 3;
        const int  ko = (tt + 3) * TBK;

        // stages first (longest latency, independent)
        if (st) {
            load_lds16(Ag  + ko, &SMEM[sb][wid * 512]);
            load_lds16(Ag2 + ko, &SMEM[sb][4096 + wid * 512]);
            load_lds16(Bg  + ko, &SMEM[4 + sb][wid * 512]);
            load_lds16(Bg2 + ko, &SMEM[4 + sb][4096 + wid * 512]);
        }

        // all fragment reads; compiler interleaves lgkmcnt(N) with MFMAs
        bf16x8_t bv[4], av[8];
#pragma unroll
        for (int j = 0; j < 4; ++j)
            bv[j] = *reinterpret_cast<const bf16x8_t*>(pb + (wn * 64 + j * 16 + lr) * TBK + xq);
#pragma unroll
        for (int i = 0; i < 8; ++i)
            av[i] = *reinterpret_cast<const bf16x8_t*>(pa + (wm * 128 + i * 16 + lr) * TBK + xq);

        __builtin_amdgcn_s_setprio(1);
#pragma unroll
        for (int i = 0; i < 8; ++i)
#pragma unroll
            for (int j = 0; j < 4; ++j)
                acc[i][j] = __builtin_amdgcn_mfma_f32_16x16x32_bf16(av[i], bv[j], acc[i][j], 0, 0, 0);
        __builtin_amdgcn_s_setprio(0);

        // tile boundary: counted drain, never 0 mid-loop (T4)
        if (tt < NT - 3)       asm volatile("s_waitcnt vmcnt(8)" ::: "memory");
        else if (tt == NT - 3) asm volatile("s_waitcnt vmcnt(4)" ::: "memory");
        else                   asm volatile("s_waitcnt vmcnt(0)" ::: "memory");
        __builtin_amdgcn_s_barrier();
    }

    // ---- epilogue ----
    if (C_F32) {
        // f32 stores: lanes 0..15 cover 64B lines already -> direct
#pragma unroll
        for (int j = 0; j < 4; ++j) {
            int col = n0 + wn * 64 + j * 16 + lr;
            float bj = bias[col];
#pragma unroll
            for (int i = 0; i < 8; ++i) {
                int rbase = m0 + wm * 128 + i * 16 + quad * 4;
#pragma unroll
                for (int r = 0; r < 4; ++r) {
                    float v = acc[i][j][r] + bj;
                    ((float*)Cp)[(size_t)(rbase + r) * ldc + col] = v;
                }
            }
        }
    } else {
        // bf16: repack through the wave's private 16KB LDS slice (ring is
        // dead after final barrier), XOR-chunk swizzle, then dwordx4 stores.
        unsigned short* ep = &SMEM[wid][0];            // [128][64] shorts
#pragma unroll
        for (int j = 0; j < 4; ++j) {
            float bj = bias[n0 + wn * 64 + j * 16 + lr];
#pragma unroll
            for (int i = 0; i < 8; ++i) {
#pragma unroll
                for (int r = 0; r < 4; ++r) {
                    int row = i * 16 + quad * 4 + r;           // 0..127
                    int col = j * 16 + lr;                     // 0..63
                    int ch  = (col >> 3) ^ (row & 7);
                    ep[row * 64 + ch * 8 + (col & 7)] = f2bf(acc[i][j][r] + bj);
                }
            }
        }
        // wave-private slice: lgkmcnt ordering suffices (compiler-tracked)
        unsigned short* Cb = (unsigned short*)Cp;
        const int cch = lane & 7;
#pragma unroll
        for (int s = 0; s < 16; ++s) {
            int row = s * 8 + (lane >> 3);                     // 0..127
            int ch  = cch ^ (row & 7);
            uint4 v = *reinterpret_cast<const uint4*>(&ep[row * 64 + ch * 8]);
            *reinterpret_cast<uint4*>(
                Cb + (size_t)(m0 + wm * 128 + row) * ldc + n0 + wn * 64 + cch * 8) = v;
        }
    }
}

// ---------------------------------------------------------------------------
// Fallback GEMM (R3/R4-proven): padded LDS, regular staging.
// ---------------------------------------------------------------------------
#define BM 128
#define BN 128
#define BK 32
#define LDT 40

template<bool A_F32, bool C_F32, bool BT>
__global__ __launch_bounds__(256) void gemm_bias_kernel(
    const void* __restrict__ Ap, const void* __restrict__ Wp,
    const float* __restrict__ bias, void* __restrict__ Cp,
    int N, int K, int lda, int ldc)
{
    __shared__ __align__(16) unsigned short As[BM * LDT];
    __shared__ __align__(16) unsigned short Bs[BN * LDT];

    const int tid  = threadIdx.x;
    const int lane = tid & 63;
    const int wid  = tid >> 6;
    const int wm   = wid >> 1;
    const int wn   = wid & 1;
    const int quad = lane >> 4;
    const int lr   = lane & 15;

    const int m0 = blockIdx.y * BM;
    const int n0 = blockIdx.x * BN;

    f32x4_t acc[4][4];
#pragma unroll
    for (int i = 0; i < 4; ++i)
#pragma unroll
        for (int j = 0; j < 4; ++j)
            acc[i][j] = (f32x4_t){0.f, 0.f, 0.f, 0.f};

    for (int k0 = 0; k0 < K; k0 += BK) {
        if (A_F32) {
            const float* A = (const float*)Ap;
#pragma unroll
            for (int it = 0; it < 4; ++it) {
                int q   = tid + it * 256;
                int row = q >> 3;
                int col = (q & 7) * 4;
                floatx4 f = *reinterpret_cast<const floatx4*>(A + (size_t)(m0 + row) * lda + k0 + col);
                ushortx4 s;
                s.x = f2bf(f.x); s.y = f2bf(f.y); s.z = f2bf(f.z); s.w = f2bf(f.w);
                *reinterpret_cast<ushortx4*>(&As[row * LDT + col]) = s;
            }
        } else {
            const unsigned short* A = (const unsigned short*)Ap;
            int a_row = tid >> 2;
            int a_col = (tid & 3) * 8;
#pragma unroll
            for (int r = 0; r < 2; ++r) {
                int row = a_row + r * 64;
                uint4 u = *reinterpret_cast<const uint4*>(A + (size_t)(m0 + row) * lda + k0 + a_col);
                *reinterpret_cast<uint4*>(&As[row * LDT + a_col]) = u;
            }
        }
        if (BT) {
            const unsigned short* Wt = (const unsigned short*)Wp;
            int b_row = tid >> 2;
            int b_col = (tid & 3) * 8;
#pragma unroll
            for (int r = 0; r < 2; ++r) {
                int n = b_row + r * 64;
                uint4 u = *reinterpret_cast<const uint4*>(Wt + (size_t)(n0 + n) * K + k0 + b_col);
                *reinterpret_cast<uint4*>(&Bs[n * LDT + b_col]) = u;
            }
        } else {
            const float* W = (const float*)Wp;
#pragma unroll
            for (int it = 0; it < 4; ++it) {
                int q  = tid + it * 256;
                int kk = q >> 5;
                int nn = (q & 31) * 4;
                floatx4 f = *reinterpret_cast<const floatx4*>(W + (size_t)(k0 + kk) * N + n0 + nn);
                Bs[(nn + 0) * LDT + kk] = f2bf(f.x);
                Bs[(nn + 1) * LDT + kk] = f2bf(f.y);
                Bs[(nn + 2) * LDT + kk] = f2bf(f.z);
                Bs[(nn + 3) * LDT + kk] = f2bf(f.w);
            }
        }
        __syncthreads();

        bf16x8_t av[4], bv[4];
#pragma unroll
        for (int i = 0; i < 4; ++i)
            av[i] = *reinterpret_cast<const bf16x8_t*>(&As[(wm * 64 + i * 16 + lr) * LDT + quad * 8]);
#pragma unroll
        for (int j = 0; j < 4; ++j)
            bv[j] = *reinterpret_cast<const bf16x8_t*>(&Bs[(wn * 64 + j * 16 + lr) * LDT + quad * 8]);

#pragma unroll
        for (int i = 0; i < 4; ++i)
#pragma unroll
            for (int j = 0; j < 4; ++j)
                acc[i][j] = __builtin_amdgcn_mfma_f32_16x16x32_bf16(av[i], bv[j], acc[i][j], 0, 0, 0);

        __syncthreads();
    }

#pragma unroll
    for (int j = 0; j < 4; ++j) {
        int col = n0 + wn * 64 + j * 16 + lr;
        float bj = bias[col];
#pragma unroll
        for (int i = 0; i < 4; ++i) {
            int rbase = m0 + wm * 64 + i * 16 + quad * 4;
#pragma unroll
            for (int r = 0; r < 4; ++r) {
                float v = acc[i][j][r] + bj;
                size_t idx = (size_t)(rbase + r) * ldc + col;
                if (C_F32) ((float*)Cp)[idx] = v;
                else       ((unsigned short*)Cp)[idx] = f2bf(v);
            }
        }
    }
}

// ---------------------------------------------------------------------------
// Tiled neighborhood attention v3: raw-bf16 LDS + XOR-chunk swizzle.
//  - LDS holds q/k/v as raw bf16 [row][64] (128B rows), chunk c (8 shorts,
//    16B) stored at position c ^ (row & 7): every 8-consecutive-lane group
//    covers all 32 banks on both writes (phase 1) and reads (phases 2/4).
//  - phase 1 is pure uint4 copies (was: unpack8 -> 192 scalar ds_write_b32
//    per thread). bf16->f32 conversion moved to the VALU at read time
//    (1 bit-op/elem); SCALE folded into the logit (1 mul per logit).
//  - LDS/block 62KB -> 31KB: 5 resident blocks/CU.
//  - identical math/values otherwise (LDS holds the same bf16 bits).
// ---------------------------------------------------------------------------
#define NA_L 4096
#define NA_K 13
#define NA_H 16
#define NA_D 64
#define NA_SCALE 0.125f
#define TL  64
#define WIN 76          // TL + 12

__global__ __launch_bounds__(256) void na1d_tiled_kernel(
    unsigned short* qkv, const float* __restrict__ rpb)
{
    __shared__ __align__(16) unsigned short ks_b[WIN * 64];
    __shared__ __align__(16) unsigned short vs_b[WIN * 64];
    __shared__ __align__(16) unsigned short qs_b[TL * 64];
    __shared__ float wgt[TL][NA_K];

    const int bid = blockIdx.x;
    const int h  = bid & 15;
    const int lt = (bid >> 4) & 63;
    const int b  = bid >> 10;
    const int l0 = lt * TL;
    const int rs = l0 - 6;

    const int t = threadIdx.x;
    const size_t rowbase = (size_t)b * NA_L;

    // ---- phase 1: raw bf16 copy of q + k/v window into LDS ----
    {
        const int qr = t >> 2;            // 0..63
        const int qi = (t & 3) * 2;       // chunk pair base
        const unsigned short* qsrc = qkv + (rowbase + l0 + qr) * 3072 + h * 64 + qi * 8;
        uint4 q0 = *reinterpret_cast<const uint4*>(qsrc);
        uint4 q1 = *reinterpret_cast<const uint4*>(qsrc + 8);

        const int r0 = t >> 3;            // 0..31
        const int ci = t & 7;             // chunk
        int g0 = rs + r0;      g0 = g0 < 0 ? 0 : (g0 > NA_L - 1 ? NA_L - 1 : g0);
        int g1 = rs + r0 + 32; g1 = g1 < 0 ? 0 : (g1 > NA_L - 1 ? NA_L - 1 : g1);
        const unsigned short* p0 = qkv + (rowbase + g0) * 3072 + 1024 + h * 64 + ci * 8;
        const unsigned short* p1 = qkv + (rowbase + g1) * 3072 + 1024 + h * 64 + ci * 8;
        uint4 k0 = *reinterpret_cast<const uint4*>(p0);
        uint4 v0 = *reinterpret_cast<const uint4*>(p0 + 1024);
        uint4 k1 = *reinterpret_cast<const uint4*>(p1);
        uint4 v1 = *reinterpret_cast<const uint4*>(p1 + 1024);
        uint4 k2, v2;
        if (t < 96) {
            int g2 = rs + r0 + 64; g2 = g2 < 0 ? 0 : (g2 > NA_L - 1 ? NA_L - 1 : g2);
            const unsigned short* p2 = qkv + (rowbase + g2) * 3072 + 1024 + h * 64 + ci * 8;
            k2 = *reinterpret_cast<const uint4*>(p2);
            v2 = *reinterpret_cast<const uint4*>(p2 + 1024);
        }

        const int qk = qr & 7;
        *reinterpret_cast<uint4*>(qs_b + qr * 64 + (( qi      ^ qk) * 8)) = q0;
        *reinterpret_cast<uint4*>(qs_b + qr * 64 + (((qi + 1) ^ qk) * 8)) = q1;
        const int rk = r0 & 7;            // (r0+32)&7 == (r0+64)&7 == r0&7
        *reinterpret_cast<uint4*>(ks_b +  r0       * 64 + ((ci ^ rk) * 8)) = k0;
        *reinterpret_cast<uint4*>(vs_b +  r0       * 64 + ((ci ^ rk) * 8)) = v0;
        *reinterpret_cast<uint4*>(ks_b + (r0 + 32) * 64 + ((ci ^ rk) * 8)) = k1;
        *reinterpret_cast<uint4*>(vs_b + (r0 + 32) * 64 + ((ci ^ rk) * 8)) = v1;
        if (t < 96) {
            *reinterpret_cast<uint4*>(ks_b + (r0 + 64) * 64 + ((ci ^ rk) * 8)) = k2;
            *reinterpret_cast<uint4*>(vs_b + (r0 + 64) * 64 + ((ci ^ rk) * 8)) = v2;
        }
    }
    __syncthreads();

    // ---- phase 2: logits; wave jb handles j = 4jb..4jb+3 for lane's l ----
    {
        const int l  = t & 63;
        const int jb = (t >> 6) * 4;
        int ig = l0 + l;
        int ni = ig - 6;
        if (ni < 0) ni = 0;
        if (ni > NA_L - NA_K) ni = NA_L - NA_K;
        int rid = ni - rs;                    // 0..63
        int pi  = ni - ig + 12;

        // row indices (clamp: rows >= WIN are discarded anyway; keep in-bounds)
        int r0r = rid + jb + 0; if (r0r > WIN - 1) r0r = WIN - 1;
        int r1r = rid + jb + 1; if (r1r > WIN - 1) r1r = WIN - 1;
        int r2r = rid + jb + 2; if (r2r > WIN - 1) r2r = WIN - 1;
        int r3r = rid + jb + 3; if (r3r > WIN - 1) r3r = WIN - 1;

        const unsigned short* qrow = qs_b + l * 64;
        const unsigned short* k0p  = ks_b + r0r * 64;
        const unsigned short* k1p  = ks_b + r1r * 64;
        const unsigned short* k2p  = ks_b + r2r * 64;
        const unsigned short* k3p  = ks_b + r3r * 64;
        const int qk = l & 7;
        const int x0 = r0r & 7, x1 = r1r & 7, x2 = r2r & 7, x3 = r3r & 7;

        floatx4 a0 = {0,0,0,0}, a1 = {0,0,0,0}, a2 = {0,0,0,0}, a3 = {0,0,0,0};
#pragma unroll
        for (int c = 0; c < 8; ++c) {
            floatx4 ql, qh, kl, kh;
            cvt8(*reinterpret_cast<const uint4*>(qrow + ((c ^ qk) * 8)), ql, qh);
            cvt8(*reinterpret_cast<const uint4*>(k0p + ((c ^ x0) * 8)), kl, kh);
            a0 += ql * kl; a0 += qh * kh;
            cvt8(*reinterpret_cast<const uint4*>(k1p + ((c ^ x1) * 8)), kl, kh);
            a1 += ql * kl; a1 += qh * kh;
            cvt8(*reinterpret_cast<const uint4*>(k2p + ((c ^ x2) * 8)), kl, kh);
            a2 += ql * kl; a2 += qh * kh;
            cvt8(*reinterpret_cast<const uint4*>(k3p + ((c ^ x3) * 8)), kl, kh);
            a3 += ql * kl; a3 += qh * kh;
        }
        float s0 = (a0.x + a0.y + a0.z + a0.w) * NA_SCALE;
        float s1 = (a1.x + a1.y + a1.z + a1.w) * NA_SCALE;
        float s2 = (a2.x + a2.y + a2.z + a2.w) * NA_SCALE;
        float s3 = (a3.x + a3.y + a3.z + a3.w) * NA_SCALE;
        const float* rp = rpb + h * 25 + pi;
        if (jb + 0 < NA_K) wgt[l][jb + 0] = s0 + rp[jb + 0];
        if (jb + 1 < NA_K) wgt[l][jb + 1] = s1 + rp[jb + 1];
        if (jb + 2 < NA_K) wgt[l][jb + 2] = s2 + rp[jb + 2];
        if (jb + 3 < NA_K) wgt[l][jb + 3] = s3 + rp[jb + 3];
    }
    __syncthreads();

    // ---- phase 3: softmax per l ----
    if (t < TL) {
        float m = -1e30f;
#pragma unroll
        for (int j = 0; j < NA_K; ++j) m = fmaxf(m, wgt[t][j]);
        float sum = 0.f;
#pragma unroll
        for (int j = 0; j < NA_K; ++j) {
            float e = expf(wgt[t][j] - m);
            wgt[t][j] = e;
            sum += e;
        }
        float inv = 1.f / sum;
#pragma unroll
        for (int j = 0; j < NA_K; ++j) wgt[t][j] *= inv;
    }
    __syncthreads();

    // ---- phase 4: AV. thread (l, 16-d chunk), bf16 reads + on-the-fly cvt ----
    {
        const int l  = t & 63;
        const int wv = t >> 6;            // 0..3 -> dims wv*16..wv*16+15
        int ig = l0 + l;
        int ni = ig - 6;
        if (ni < 0) ni = 0;
        if (ni > NA_L - NA_K) ni = NA_L - NA_K;
        int rid = ni - rs;
        floatx4 o0 = {0,0,0,0}, o1 = {0,0,0,0}, o2 = {0,0,0,0}, o3 = {0,0,0,0};
#pragma unroll
        for (int j = 0; j < NA_K; ++j) {
            float w = wgt[l][j];
            int r = rid + j;
            int key = r & 7;
            const unsigned short* vrow = vs_b + r * 64;
            floatx4 xl, xh;
            cvt8(*reinterpret_cast<const uint4*>(vrow + (((2 * wv)     ^ key) * 8)), xl, xh);
            o0 += w * xl; o1 += w * xh;
            cvt8(*reinterpret_cast<const uint4*>(vrow + (((2 * wv + 1) ^ key) * 8)), xl, xh);
            o2 += w * xl; o3 += w * xh;
        }
        unsigned short* dst = qkv + (rowbase + ig) * 3072 + h * 64 + wv * 16;
        uint4 p0, p1;
        p0.x = (unsigned int)f2bf(o0.x) | ((unsigned int)f2bf(o0.y) << 16);
        p0.y = (unsigned int)f2bf(o0.z) | ((unsigned int)f2bf(o0.w) << 16);
        p0.z = (unsigned int)f2bf(o1.x) | ((unsigned int)f2bf(o1.y) << 16);
        p0.w = (unsigned int)f2bf(o1.z) | ((unsigned int)f2bf(o1.w) << 16);
        p1.x = (unsigned int)f2bf(o2.x) | ((unsigned int)f2bf(o2.y) << 16);
        p1.y = (unsigned int)f2bf(o2.z) | ((unsigned int)f2bf(o2.w) << 16);
        p1.z = (unsigned int)f2bf(o3.x) | ((unsigned int)f2bf(o3.y) << 16);
        p1.w = (unsigned int)f2bf(o3.z) | ((unsigned int)f2bf(o3.w) << 16);
        *reinterpret_cast<uint4*>(dst)     = p0;
        *reinterpret_cast<uint4*>(dst + 8) = p1;
    }
}

// ---------------------------------------------------------------------------
extern "C" void kernel_launch(void* const* d_in, const int* in_sizes, int n_in,
                              void* d_out, int out_size, void* d_ws, size_t ws_size,
                              hipStream_t stream)
{
    const float* x      = (const float*)d_in[0];
    const float* w_qkv  = (const float*)d_in[1];
    const float* b_qkv  = (const float*)d_in[2];
    const float* rpb    = (const float*)d_in[3];
    const float* w_proj = (const float*)d_in[4];
    const float* b_proj = (const float*)d_in[5];
    float* out = (float*)d_out;

    const int M  = 4 * 4096;   // 16384
    const int K  = 1024;
    const int N1 = 3072;
    const int N2 = 1024;

    unsigned short* qkv = (unsigned short*)d_ws;              // 96 MiB
    unsigned short* Wt1 = qkv + (size_t)M * N1;               // 6 MiB
    unsigned short* Wt2 = Wt1 + (size_t)N1 * K;               // 2 MiB
    unsigned short* xb  = Wt2 + (size_t)N2 * K;               // 32 MiB
    size_t need_mid  = ((size_t)M * N1 + (size_t)N1 * K + (size_t)N2 * K) * 2;
    size_t need_fast = need_mid + (size_t)M * K * 2;

    const int na_grid = 4 * (NA_L / TL) * NA_H;               // 4096

    if (ws_size >= need_fast) {
        convert_f32_bf16<<<dim3(M * K / (256 * 8)), 256, 0, stream>>>(x, xb);
        transpose_f32_to_bf16<<<dim3(N1 / 32, K / 32), 256, 0, stream>>>(w_qkv, Wt1, K, N1);
        transpose_f32_to_bf16<<<dim3(N2 / 32, K / 32), 256, 0, stream>>>(w_proj, Wt2, K, N2);
        gemm_pipe_kernel<false><<<dim3(N1 / TBN, M / TBM), 512, 0, stream>>>(
            xb, Wt1, b_qkv, qkv, N1, K, K, N1);
        na1d_tiled_kernel<<<dim3(na_grid), 256, 0, stream>>>(qkv, rpb);
        gemm_pipe_kernel<true><<<dim3(N2 / TBN, M / TBM), 512, 0, stream>>>(
            qkv, Wt2, b_proj, out, N2, K, N1, N2);
    } else if (ws_size >= need_mid) {
        transpose_f32_to_bf16<<<dim3(N1 / 32, K / 32), 256, 0, stream>>>(w_qkv, Wt1, K, N1);
        transpose_f32_to_bf16<<<dim3(N2 / 32, K / 32), 256, 0, stream>>>(w_proj, Wt2, K, N2);
        gemm_bias_kernel<true, false, true><<<dim3(N1 / BN, M / BM), 256, 0, stream>>>(
            x, Wt1, b_qkv, qkv, N1, K, K, N1);
        na1d_tiled_kernel<<<dim3(na_grid), 256, 0, stream>>>(qkv, rpb);
        gemm_bias_kernel<false, true, true><<<dim3(N2 / BN, M / BM), 256, 0, stream>>>(
            qkv, Wt2, b_proj, out, N2, K, N1, N2);
    } else {
        gemm_bias_kernel<true, false, false><<<dim3(N1 / BN, M / BM), 256, 0, stream>>>(
            x, w_qkv, b_qkv, qkv, N1, K, K, N1);
        na1d_tiled_kernel<<<dim3(na_grid), 256, 0, stream>>>(qkv, rpb);
        gemm_bias_kernel<false, true, false><<<dim3(N2 / BN, M / BM), 256, 0, stream>>>(
            qkv, w_proj, b_proj, out, N2, K, N1, N2);
    }
}

// Round 7
// 335.321 us; speedup vs baseline: 1.2594x; 1.0362x over previous
//
#include <hip/hip_runtime.h>

typedef __bf16 bf16x8_t __attribute__((ext_vector_type(8)));
typedef float  f32x4_t  __attribute__((ext_vector_type(4)));
typedef float  floatx4  __attribute__((ext_vector_type(4)));
typedef unsigned short ushortx4 __attribute__((ext_vector_type(4)));

__device__ __forceinline__ float bf2f(unsigned short u) {
    union { unsigned int i; float f; } c; c.i = ((unsigned int)u) << 16; return c.f;
}
__device__ __forceinline__ unsigned short f2bf(float f) {
    union { float f; unsigned int i; } c; c.f = f;
    unsigned int u = c.i;
    u += 0x7fffu + ((u >> 16) & 1u);   // RNE
    return (unsigned short)(u >> 16);
}
// 8 packed bf16 (as uint4) -> 2 float4, pure bit ops (1 VALU op/elem)
__device__ __forceinline__ void cvt8(uint4 u, floatx4& lo, floatx4& hi) {
    union { unsigned int i; float f; } c;
    c.i = u.x << 16;          lo.x = c.f;
    c.i = u.x & 0xffff0000u;  lo.y = c.f;
    c.i = u.y << 16;          lo.z = c.f;
    c.i = u.y & 0xffff0000u;  lo.w = c.f;
    c.i = u.z << 16;          hi.x = c.f;
    c.i = u.z & 0xffff0000u;  hi.y = c.f;
    c.i = u.w << 16;          hi.z = c.f;
    c.i = u.w & 0xffff0000u;  hi.w = c.f;
}

// async global->LDS, 16 B per lane; lds dest = wave-uniform base + lane*16
__device__ __forceinline__ void load_lds16(const unsigned short* g, unsigned short* l) {
    __builtin_amdgcn_global_load_lds(
        (const __attribute__((address_space(1))) unsigned int*)g,
        (__attribute__((address_space(3))) unsigned int*)l, 16, 0, 0);
}

// ---------------------------------------------------------------------------
// x (f32) -> bf16, 8 elems/thread
// ---------------------------------------------------------------------------
__global__ __launch_bounds__(256) void convert_f32_bf16(
    const float* __restrict__ x, unsigned short* __restrict__ xb)
{
    size_t i = ((size_t)blockIdx.x * 256 + threadIdx.x) * 8;
    floatx4 a = *reinterpret_cast<const floatx4*>(x + i);
    floatx4 b = *reinterpret_cast<const floatx4*>(x + i + 4);
    uint4 o;
    o.x = (unsigned int)f2bf(a.x) | ((unsigned int)f2bf(a.y) << 16);
    o.y = (unsigned int)f2bf(a.z) | ((unsigned int)f2bf(a.w) << 16);
    o.z = (unsigned int)f2bf(b.x) | ((unsigned int)f2bf(b.y) << 16);
    o.w = (unsigned int)f2bf(b.z) | ((unsigned int)f2bf(b.w) << 16);
    *reinterpret_cast<uint4*>(xb + i) = o;
}

// ---------------------------------------------------------------------------
// Weight prep: Wt[n][k] (bf16) = W[k][n] (f32). 32x32 LDS-tiled transpose.
// ---------------------------------------------------------------------------
__global__ __launch_bounds__(256) void transpose_f32_to_bf16(
    const float* __restrict__ W, unsigned short* __restrict__ Wt,
    int Kdim, int Ndim)
{
    __shared__ float tile[32][33];
    const int n0 = blockIdx.x * 32, k0 = blockIdx.y * 32;
    const int tx = threadIdx.x & 31, ty = threadIdx.x >> 5;   // ty 0..7
#pragma unroll
    for (int r = 0; r < 4; ++r) {
        int k = ty + r * 8;
        tile[k][tx] = W[(size_t)(k0 + k) * Ndim + n0 + tx];
    }
    __syncthreads();
#pragma unroll
    for (int r = 0; r < 4; ++r) {
        int n = ty + r * 8;
        Wt[(size_t)(n0 + n) * Kdim + k0 + tx] = f2bf(tile[tx][n]);
    }
}

// ---------------------------------------------------------------------------
// 256x256-tile, 8-wave (2Mx4N), v4: BK=64, dbuf2 JIT pipeline.
//  - LDS: A[2][256][64] + B[2][256][64] bf16 = 128 KiB exactly.
//    (offset arithmetic only — NO arrays of LDS pointers: hipcc cannot emit
//     the addrspacecast static initializer; that was R6's compile failure.)
//  - ONE barrier per 64-K tile; 64 MFMA per wave per window.
//  - JIT staging: at tile tau start, issue the 8 global_load_lds for tile
//    tau+1 into buf (tau+1)&1 (its last reader was tile tau-1, done at the
//    previous barrier -> no write/read overlap). vmcnt(0) at tile end is
//    ~free: issue-to-wait distance = full MFMA window (~2000cy) > ~900cy HBM.
//  - XOR swizzle (8 chunks/row): write key s_row8&7, read key lr&7; both
//    equal row&7 -> consistent; reads 2-way bank aliased (free).
//  - XCD-aware bijective blockIdx swizzle (T1); grid %8==0 both call sites.
//  - bf16 epilogue via per-wave LDS repack (R3-proven, WRITE_SIZE 98MB).
// Requires: M%256==0, N%256==0, K%64==0, grid %8==0.
// ---------------------------------------------------------------------------
#define TBM 256
#define TBN 256
#define TBK 64

template<bool C_F32>
__global__ __launch_bounds__(512, 2) void gemm_pipe_kernel(
    const unsigned short* __restrict__ A, const unsigned short* __restrict__ Wt,
    const float* __restrict__ bias, void* __restrict__ Cp,
    int N, int K, int lda, int ldc)
{
    __shared__ __align__(16) unsigned short SMEM[65536];   // 128 KiB

    const int tid  = threadIdx.x;
    const int lane = tid & 63;
    const int wid  = tid >> 6;        // 0..7
    const int wm   = wid >> 2;        // 0..1  (M half: 128 rows)
    const int wn   = wid & 3;         // 0..3  (N quarter: 64 cols)
    const int quad = lane >> 4;       // 0..3
    const int lr   = lane & 15;       // 0..15

    // XCD-aware bijective swizzle (nwg % 8 == 0 at both call sites)
    const int gx  = gridDim.x;
    const int cpx = (gx * gridDim.y) >> 3;
    const int bid = blockIdx.y * gx + blockIdx.x;
    const int nid = (bid & 7) * cpx + (bid >> 3);
    const int m0 = (nid / gx) * TBM;
    const int n0 = (nid % gx) * TBN;

    const int s_row8 = tid >> 3;                               // 0..63
    const int c_sw   = ((tid & 7) ^ (s_row8 & 7)) * 8;         // source chunk (pre-swizzled)
    const int NT     = K >> 6;

    const unsigned short* Ag = A  + (size_t)(m0 + s_row8) * lda + c_sw;
    const unsigned short* Bg = Wt + (size_t)(n0 + s_row8) * K   + c_sw;

    // buffer layout (shorts): A0 @0, A1 @16384, B0 @32768, B1 @49152
    const int sdst = wid * 512;        // + r*4096 per 64-row round

    f32x4_t acc[8][4];
#pragma unroll
    for (int i = 0; i < 8; ++i)
#pragma unroll
        for (int j = 0; j < 4; ++j)
            acc[i][j] = (f32x4_t){0.f, 0.f, 0.f, 0.f};

    // ---- prologue: stage tile 0 into buf 0 ----
#pragma unroll
    for (int r = 0; r < 4; ++r) {
        load_lds16(Ag + (size_t)(r * 64) * lda, SMEM + r * 4096 + sdst);
        load_lds16(Bg + (size_t)(r * 64) * K,   SMEM + 32768 + r * 4096 + sdst);
    }
    asm volatile("s_waitcnt vmcnt(0)" ::: "memory");
    __builtin_amdgcn_s_barrier();

    const int xk = lr & 7;             // read-side swizzle key (= row&7)

    for (int tau = 0; tau < NT; ++tau) {
        const int doff = (tau & 1) * 16384;
        const unsigned short* pa = SMEM + doff;
        const unsigned short* pb = SMEM + 32768 + doff;

        // JIT stage tile tau+1 into the other buffer (reader finished last barrier)
        if (tau + 1 < NT) {
            const int noff = ((tau + 1) & 1) * 16384;
            unsigned short* na = SMEM + noff;
            unsigned short* nb = SMEM + 32768 + noff;
            const size_t ko = (size_t)(tau + 1) * TBK;
#pragma unroll
            for (int r = 0; r < 4; ++r) {
                load_lds16(Ag + (size_t)(r * 64) * lda + ko, na + r * 4096 + sdst);
                load_lds16(Bg + (size_t)(r * 64) * K   + ko, nb + r * 4096 + sdst);
            }
        }

        bf16x8_t av[8], bv[4];
        // ---- k-half 0: chunk = quad ----
#pragma unroll
        for (int j = 0; j < 4; ++j)
            bv[j] = *reinterpret_cast<const bf16x8_t*>(
                pb + (wn * 64 + j * 16 + lr) * 64 + ((quad ^ xk) * 8));
#pragma unroll
        for (int i = 0; i < 8; ++i)
            av[i] = *reinterpret_cast<const bf16x8_t*>(
                pa + (wm * 128 + i * 16 + lr) * 64 + ((quad ^ xk) * 8));
        __builtin_amdgcn_s_setprio(1);
#pragma unroll
        for (int i = 0; i < 8; ++i)
#pragma unroll
            for (int j = 0; j < 4; ++j)
                acc[i][j] = __builtin_amdgcn_mfma_f32_16x16x32_bf16(av[i], bv[j], acc[i][j], 0, 0, 0);
        __builtin_amdgcn_s_setprio(0);

        // ---- k-half 1: chunk = 4 + quad ----
#pragma unroll
        for (int j = 0; j < 4; ++j)
            bv[j] = *reinterpret_cast<const bf16x8_t*>(
                pb + (wn * 64 + j * 16 + lr) * 64 + (((4 + quad) ^ xk) * 8));
#pragma unroll
        for (int i = 0; i < 8; ++i)
            av[i] = *reinterpret_cast<const bf16x8_t*>(
                pa + (wm * 128 + i * 16 + lr) * 64 + (((4 + quad) ^ xk) * 8));
        __builtin_amdgcn_s_setprio(1);
#pragma unroll
        for (int i = 0; i < 8; ++i)
#pragma unroll
            for (int j = 0; j < 4; ++j)
                acc[i][j] = __builtin_amdgcn_mfma_f32_16x16x32_bf16(av[i], bv[j], acc[i][j], 0, 0, 0);
        __builtin_amdgcn_s_setprio(0);

        // tile boundary: next tile fully resident (issued one full window ago)
        asm volatile("s_waitcnt vmcnt(0)" ::: "memory");
        __builtin_amdgcn_s_barrier();
    }

    // ---- epilogue ----
    if (C_F32) {
#pragma unroll
        for (int j = 0; j < 4; ++j) {
            int col = n0 + wn * 64 + j * 16 + lr;
            float bj = bias[col];
#pragma unroll
            for (int i = 0; i < 8; ++i) {
                int rbase = m0 + wm * 128 + i * 16 + quad * 4;
#pragma unroll
                for (int r = 0; r < 4; ++r) {
                    float v = acc[i][j][r] + bj;
                    ((float*)Cp)[(size_t)(rbase + r) * ldc + col] = v;
                }
            }
        }
    } else {
        // bf16: repack through the wave's private 16KB LDS slice (ring dead
        // after final barrier), XOR-chunk swizzle, then dwordx4 stores.
        unsigned short* ep = SMEM + wid * 8192;        // [128][64] shorts
#pragma unroll
        for (int j = 0; j < 4; ++j) {
            float bj = bias[n0 + wn * 64 + j * 16 + lr];
#pragma unroll
            for (int i = 0; i < 8; ++i) {
#pragma unroll
                for (int r = 0; r < 4; ++r) {
                    int row = i * 16 + quad * 4 + r;           // 0..127
                    int col = j * 16 + lr;                     // 0..63
                    int ch  = (col >> 3) ^ (row & 7);
                    ep[row * 64 + ch * 8 + (col & 7)] = f2bf(acc[i][j][r] + bj);
                }
            }
        }
        unsigned short* Cb = (unsigned short*)Cp;
        const int cch = lane & 7;
#pragma unroll
        for (int s = 0; s < 16; ++s) {
            int row = s * 8 + (lane >> 3);                     // 0..127
            int ch  = cch ^ (row & 7);
            uint4 v = *reinterpret_cast<const uint4*>(&ep[row * 64 + ch * 8]);
            *reinterpret_cast<uint4*>(
                Cb + (size_t)(m0 + wm * 128 + row) * ldc + n0 + wn * 64 + cch * 8) = v;
        }
    }
}

// ---------------------------------------------------------------------------
// Fallback GEMM (R3/R4-proven): padded LDS, regular staging.
// ---------------------------------------------------------------------------
#define BM 128
#define BN 128
#define BK 32
#define LDT 40

template<bool A_F32, bool C_F32, bool BT>
__global__ __launch_bounds__(256) void gemm_bias_kernel(
    const void* __restrict__ Ap, const void* __restrict__ Wp,
    const float* __restrict__ bias, void* __restrict__ Cp,
    int N, int K, int lda, int ldc)
{
    __shared__ __align__(16) unsigned short As[BM * LDT];
    __shared__ __align__(16) unsigned short Bs[BN * LDT];

    const int tid  = threadIdx.x;
    const int lane = tid & 63;
    const int wid  = tid >> 6;
    const int wm   = wid >> 1;
    const int wn   = wid & 1;
    const int quad = lane >> 4;
    const int lr   = lane & 15;

    const int m0 = blockIdx.y * BM;
    const int n0 = blockIdx.x * BN;

    f32x4_t acc[4][4];
#pragma unroll
    for (int i = 0; i < 4; ++i)
#pragma unroll
        for (int j = 0; j < 4; ++j)
            acc[i][j] = (f32x4_t){0.f, 0.f, 0.f, 0.f};

    for (int k0 = 0; k0 < K; k0 += BK) {
        if (A_F32) {
            const float* A = (const float*)Ap;
#pragma unroll
            for (int it = 0; it < 4; ++it) {
                int q   = tid + it * 256;
                int row = q >> 3;
                int col = (q & 7) * 4;
                floatx4 f = *reinterpret_cast<const floatx4*>(A + (size_t)(m0 + row) * lda + k0 + col);
                ushortx4 s;
                s.x = f2bf(f.x); s.y = f2bf(f.y); s.z = f2bf(f.z); s.w = f2bf(f.w);
                *reinterpret_cast<ushortx4*>(&As[row * LDT + col]) = s;
            }
        } else {
            const unsigned short* A = (const unsigned short*)Ap;
            int a_row = tid >> 2;
            int a_col = (tid & 3) * 8;
#pragma unroll
            for (int r = 0; r < 2; ++r) {
                int row = a_row + r * 64;
                uint4 u = *reinterpret_cast<const uint4*>(A + (size_t)(m0 + row) * lda + k0 + a_col);
                *reinterpret_cast<uint4*>(&As[row * LDT + a_col]) = u;
            }
        }
        if (BT) {
            const unsigned short* Wt = (const unsigned short*)Wp;
            int b_row = tid >> 2;
            int b_col = (tid & 3) * 8;
#pragma unroll
            for (int r = 0; r < 2; ++r) {
                int n = b_row + r * 64;
                uint4 u = *reinterpret_cast<const uint4*>(Wt + (size_t)(n0 + n) * K + k0 + b_col);
                *reinterpret_cast<uint4*>(&Bs[n * LDT + b_col]) = u;
            }
        } else {
            const float* W = (const float*)Wp;
#pragma unroll
            for (int it = 0; it < 4; ++it) {
                int q  = tid + it * 256;
                int kk = q >> 5;
                int nn = (q & 31) * 4;
                floatx4 f = *reinterpret_cast<const floatx4*>(W + (size_t)(k0 + kk) * N + n0 + nn);
                Bs[(nn + 0) * LDT + kk] = f2bf(f.x);
                Bs[(nn + 1) * LDT + kk] = f2bf(f.y);
                Bs[(nn + 2) * LDT + kk] = f2bf(f.z);
                Bs[(nn + 3) * LDT + kk] = f2bf(f.w);
            }
        }
        __syncthreads();

        bf16x8_t av[4], bv[4];
#pragma unroll
        for (int i = 0; i < 4; ++i)
            av[i] = *reinterpret_cast<const bf16x8_t*>(&As[(wm * 64 + i * 16 + lr) * LDT + quad * 8]);
#pragma unroll
        for (int j = 0; j < 4; ++j)
            bv[j] = *reinterpret_cast<const bf16x8_t*>(&Bs[(wn * 64 + j * 16 + lr) * LDT + quad * 8]);

#pragma unroll
        for (int i = 0; i < 4; ++i)
#pragma unroll
            for (int j = 0; j < 4; ++j)
                acc[i][j] = __builtin_amdgcn_mfma_f32_16x16x32_bf16(av[i], bv[j], acc[i][j], 0, 0, 0);

        __syncthreads();
    }

#pragma unroll
    for (int j = 0; j < 4; ++j) {
        int col = n0 + wn * 64 + j * 16 + lr;
        float bj = bias[col];
#pragma unroll
        for (int i = 0; i < 4; ++i) {
            int rbase = m0 + wm * 64 + i * 16 + quad * 4;
#pragma unroll
            for (int r = 0; r < 4; ++r) {
                float v = acc[i][j][r] + bj;
                size_t idx = (size_t)(rbase + r) * ldc + col;
                if (C_F32) ((float*)Cp)[idx] = v;
                else       ((unsigned short*)Cp)[idx] = f2bf(v);
            }
        }
    }
}

// ---------------------------------------------------------------------------
// Tiled neighborhood attention v4 = v3 + XCD-aware bid swizzle.
//  All 16 heads of one (b,lt) group read the SAME 76 qkv rows (different
//  128B slices). Default dispatch round-robins consecutive blocks over 8
//  XCDs -> 16 heads hit 8 different L2s, each re-fetching from HBM. The
//  bijective swizzle (grid 4096 % 8 == 0) gives each XCD 512 consecutive
//  logical blocks = 32 whole (b,lt) groups -> 1 HBM fetch + 15 L2 hits.
// ---------------------------------------------------------------------------
#define NA_L 4096
#define NA_K 13
#define NA_H 16
#define NA_D 64
#define NA_SCALE 0.125f
#define TL  64
#define WIN 76          // TL + 12

__global__ __launch_bounds__(256) void na1d_tiled_kernel(
    unsigned short* qkv, const float* __restrict__ rpb)
{
    __shared__ __align__(16) unsigned short ks_b[WIN * 64];
    __shared__ __align__(16) unsigned short vs_b[WIN * 64];
    __shared__ __align__(16) unsigned short qs_b[TL * 64];
    __shared__ float wgt[TL][NA_K];

    // XCD-aware bijective swizzle: hw-consecutive blocks (same XCD stride 8)
    // -> logically consecutive (same (b,lt) group on one XCD).
    const int cpx = gridDim.x >> 3;
    const int hb  = blockIdx.x;
    const int bid = (hb & 7) * cpx + (hb >> 3);

    const int h  = bid & 15;
    const int lt = (bid >> 4) & 63;
    const int b  = bid >> 10;
    const int l0 = lt * TL;
    const int rs = l0 - 6;

    const int t = threadIdx.x;
    const size_t rowbase = (size_t)b * NA_L;

    // ---- phase 1: raw bf16 copy of q + k/v window into LDS ----
    {
        const int qr = t >> 2;            // 0..63
        const int qi = (t & 3) * 2;       // chunk pair base
        const unsigned short* qsrc = qkv + (rowbase + l0 + qr) * 3072 + h * 64 + qi * 8;
        uint4 q0 = *reinterpret_cast<const uint4*>(qsrc);
        uint4 q1 = *reinterpret_cast<const uint4*>(qsrc + 8);

        const int r0 = t >> 3;            // 0..31
        const int ci = t & 7;             // chunk
        int g0 = rs + r0;      g0 = g0 < 0 ? 0 : (g0 > NA_L - 1 ? NA_L - 1 : g0);
        int g1 = rs + r0 + 32; g1 = g1 < 0 ? 0 : (g1 > NA_L - 1 ? NA_L - 1 : g1);
        const unsigned short* p0 = qkv + (rowbase + g0) * 3072 + 1024 + h * 64 + ci * 8;
        const unsigned short* p1 = qkv + (rowbase + g1) * 3072 + 1024 + h * 64 + ci * 8;
        uint4 k0 = *reinterpret_cast<const uint4*>(p0);
        uint4 v0 = *reinterpret_cast<const uint4*>(p0 + 1024);
        uint4 k1 = *reinterpret_cast<const uint4*>(p1);
        uint4 v1 = *reinterpret_cast<const uint4*>(p1 + 1024);
        uint4 k2, v2;
        if (t < 96) {
            int g2 = rs + r0 + 64; g2 = g2 < 0 ? 0 : (g2 > NA_L - 1 ? NA_L - 1 : g2);
            const unsigned short* p2 = qkv + (rowbase + g2) * 3072 + 1024 + h * 64 + ci * 8;
            k2 = *reinterpret_cast<const uint4*>(p2);
            v2 = *reinterpret_cast<const uint4*>(p2 + 1024);
        }

        const int qk = qr & 7;
        *reinterpret_cast<uint4*>(qs_b + qr * 64 + (( qi      ^ qk) * 8)) = q0;
        *reinterpret_cast<uint4*>(qs_b + qr * 64 + (((qi + 1) ^ qk) * 8)) = q1;
        const int rk = r0 & 7;            // (r0+32)&7 == (r0+64)&7 == r0&7
        *reinterpret_cast<uint4*>(ks_b +  r0       * 64 + ((ci ^ rk) * 8)) = k0;
        *reinterpret_cast<uint4*>(vs_b +  r0       * 64 + ((ci ^ rk) * 8)) = v0;
        *reinterpret_cast<uint4*>(ks_b + (r0 + 32) * 64 + ((ci ^ rk) * 8)) = k1;
        *reinterpret_cast<uint4*>(vs_b + (r0 + 32) * 64 + ((ci ^ rk) * 8)) = v1;
        if (t < 96) {
            *reinterpret_cast<uint4*>(ks_b + (r0 + 64) * 64 + ((ci ^ rk) * 8)) = k2;
            *reinterpret_cast<uint4*>(vs_b + (r0 + 64) * 64 + ((ci ^ rk) * 8)) = v2;
        }
    }
    __syncthreads();

    // ---- phase 2: logits; wave jb handles j = 4jb..4jb+3 for lane's l ----
    {
        const int l  = t & 63;
        const int jb = (t >> 6) * 4;
        int ig = l0 + l;
        int ni = ig - 6;
        if (ni < 0) ni = 0;
        if (ni > NA_L - NA_K) ni = NA_L - NA_K;
        int rid = ni - rs;                    // 0..63
        int pi  = ni - ig + 12;

        int r0r = rid + jb + 0; if (r0r > WIN - 1) r0r = WIN - 1;
        int r1r = rid + jb + 1; if (r1r > WIN - 1) r1r = WIN - 1;
        int r2r = rid + jb + 2; if (r2r > WIN - 1) r2r = WIN - 1;
        int r3r = rid + jb + 3; if (r3r > WIN - 1) r3r = WIN - 1;

        const unsigned short* qrow = qs_b + l * 64;
        const unsigned short* k0p  = ks_b + r0r * 64;
        const unsigned short* k1p  = ks_b + r1r * 64;
        const unsigned short* k2p  = ks_b + r2r * 64;
        const unsigned short* k3p  = ks_b + r3r * 64;
        const int qk = l & 7;
        const int x0 = r0r & 7, x1 = r1r & 7, x2 = r2r & 7, x3 = r3r & 7;

        floatx4 a0 = {0,0,0,0}, a1 = {0,0,0,0}, a2 = {0,0,0,0}, a3 = {0,0,0,0};
#pragma unroll
        for (int c = 0; c < 8; ++c) {
            floatx4 ql, qh, kl, kh;
            cvt8(*reinterpret_cast<const uint4*>(qrow + ((c ^ qk) * 8)), ql, qh);
            cvt8(*reinterpret_cast<const uint4*>(k0p + ((c ^ x0) * 8)), kl, kh);
            a0 += ql * kl; a0 += qh * kh;
            cvt8(*reinterpret_cast<const uint4*>(k1p + ((c ^ x1) * 8)), kl, kh);
            a1 += ql * kl; a1 += qh * kh;
            cvt8(*reinterpret_cast<const uint4*>(k2p + ((c ^ x2) * 8)), kl, kh);
            a2 += ql * kl; a2 += qh * kh;
            cvt8(*reinterpret_cast<const uint4*>(k3p + ((c ^ x3) * 8)), kl, kh);
            a3 += ql * kl; a3 += qh * kh;
        }
        float s0 = (a0.x + a0.y + a0.z + a0.w) * NA_SCALE;
        float s1 = (a1.x + a1.y + a1.z + a1.w) * NA_SCALE;
        float s2 = (a2.x + a2.y + a2.z + a2.w) * NA_SCALE;
        float s3 = (a3.x + a3.y + a3.z + a3.w) * NA_SCALE;
        const float* rp = rpb + h * 25 + pi;
        if (jb + 0 < NA_K) wgt[l][jb + 0] = s0 + rp[jb + 0];
        if (jb + 1 < NA_K) wgt[l][jb + 1] = s1 + rp[jb + 1];
        if (jb + 2 < NA_K) wgt[l][jb + 2] = s2 + rp[jb + 2];
        if (jb + 3 < NA_K) wgt[l][jb + 3] = s3 + rp[jb + 3];
    }
    __syncthreads();

    // ---- phase 3: softmax per l ----
    if (t < TL) {
        float m = -1e30f;
#pragma unroll
        for (int j = 0; j < NA_K; ++j) m = fmaxf(m, wgt[t][j]);
        float sum = 0.f;
#pragma unroll
        for (int j = 0; j < NA_K; ++j) {
            float e = expf(wgt[t][j] - m);
            wgt[t][j] = e;
            sum += e;
        }
        float inv = 1.f / sum;
#pragma unroll
        for (int j = 0; j < NA_K; ++j) wgt[t][j] *= inv;
    }
    __syncthreads();

    // ---- phase 4: AV. thread (l, 16-d chunk), bf16 reads + on-the-fly cvt ----
    {
        const int l  = t & 63;
        const int wv = t >> 6;            // 0..3 -> dims wv*16..wv*16+15
        int ig = l0 + l;
        int ni = ig - 6;
        if (ni < 0) ni = 0;
        if (ni > NA_L - NA_K) ni = NA_L - NA_K;
        int rid = ni - rs;
        floatx4 o0 = {0,0,0,0}, o1 = {0,0,0,0}, o2 = {0,0,0,0}, o3 = {0,0,0,0};
#pragma unroll
        for (int j = 0; j < NA_K; ++j) {
            float w = wgt[l][j];
            int r = rid + j;
            int key = r & 7;
            const unsigned short* vrow = vs_b + r * 64;
            floatx4 xl, xh;
            cvt8(*reinterpret_cast<const uint4*>(vrow + (((2 * wv)     ^ key) * 8)), xl, xh);
            o0 += w * xl; o1 += w * xh;
            cvt8(*reinterpret_cast<const uint4*>(vrow + (((2 * wv + 1) ^ key) * 8)), xl, xh);
            o2 += w * xl; o3 += w * xh;
        }
        unsigned short* dst = qkv + (rowbase + ig) * 3072 + h * 64 + wv * 16;
        uint4 p0, p1;
        p0.x = (unsigned int)f2bf(o0.x) | ((unsigned int)f2bf(o0.y) << 16);
        p0.y = (unsigned int)f2bf(o0.z) | ((unsigned int)f2bf(o0.w) << 16);
        p0.z = (unsigned int)f2bf(o1.x) | ((unsigned int)f2bf(o1.y) << 16);
        p0.w = (unsigned int)f2bf(o1.z) | ((unsigned int)f2bf(o1.w) << 16);
        p1.x = (unsigned int)f2bf(o2.x) | ((unsigned int)f2bf(o2.y) << 16);
        p1.y = (unsigned int)f2bf(o2.z) | ((unsigned int)f2bf(o2.w) << 16);
        p1.z = (unsigned int)f2bf(o3.x) | ((unsigned int)f2bf(o3.y) << 16);
        p1.w = (unsigned int)f2bf(o3.z) | ((unsigned int)f2bf(o3.w) << 16);
        *reinterpret_cast<uint4*>(dst)     = p0;
        *reinterpret_cast<uint4*>(dst + 8) = p1;
    }
}

// ---------------------------------------------------------------------------
extern "C" void kernel_launch(void* const* d_in, const int* in_sizes, int n_in,
                              void* d_out, int out_size, void* d_ws, size_t ws_size,
                              hipStream_t stream)
{
    const float* x      = (const float*)d_in[0];
    const float* w_qkv  = (const float*)d_in[1];
    const float* b_qkv  = (const float*)d_in[2];
    const float* rpb    = (const float*)d_in[3];
    const float* w_proj = (const float*)d_in[4];
    const float* b_proj = (const float*)d_in[5];
    float* out = (float*)d_out;

    const int M  = 4 * 4096;   // 16384
    const int K  = 1024;
    const int N1 = 3072;
    const int N2 = 1024;

    unsigned short* qkv = (unsigned short*)d_ws;              // 96 MiB
    unsigned short* Wt1 = qkv + (size_t)M * N1;               // 6 MiB
    unsigned short* Wt2 = Wt1 + (size_t)N1 * K;               // 2 MiB
    unsigned short* xb  = Wt2 + (size_t)N2 * K;               // 32 MiB
    size_t need_mid  = ((size_t)M * N1 + (size_t)N1 * K + (size_t)N2 * K) * 2;
    size_t need_fast = need_mid + (size_t)M * K * 2;

    const int na_grid = 4 * (NA_L / TL) * NA_H;               // 4096

    if (ws_size >= need_fast) {
        convert_f32_bf16<<<dim3(M * K / (256 * 8)), 256, 0, stream>>>(x, xb);
        transpose_f32_to_bf16<<<dim3(N1 / 32, K / 32), 256, 0, stream>>>(w_qkv, Wt1, K, N1);
        transpose_f32_to_bf16<<<dim3(N2 / 32, K / 32), 256, 0, stream>>>(w_proj, Wt2, K, N2);
        gemm_pipe_kernel<false><<<dim3(N1 / TBN, M / TBM), 512, 0, stream>>>(
            xb, Wt1, b_qkv, qkv, N1, K, K, N1);
        na1d_tiled_kernel<<<dim3(na_grid), 256, 0, stream>>>(qkv, rpb);
        gemm_pipe_kernel<true><<<dim3(N2 / TBN, M / TBM), 512, 0, stream>>>(
            qkv, Wt2, b_proj, out, N2, K, N1, N2);
    } else if (ws_size >= need_mid) {
        transpose_f32_to_bf16<<<dim3(N1 / 32, K / 32), 256, 0, stream>>>(w_qkv, Wt1, K, N1);
        transpose_f32_to_bf16<<<dim3(N2 / 32, K / 32), 256, 0, stream>>>(w_proj, Wt2, K, N2);
        gemm_bias_kernel<true, false, true><<<dim3(N1 / BN, M / BM), 256, 0, stream>>>(
            x, Wt1, b_qkv, qkv, N1, K, K, N1);
        na1d_tiled_kernel<<<dim3(na_grid), 256, 0, stream>>>(qkv, rpb);
        gemm_bias_kernel<false, true, true><<<dim3(N2 / BN, M / BM), 256, 0, stream>>>(
            qkv, Wt2, b_proj, out, N2, K, N1, N2);
    } else {
        gemm_bias_kernel<true, false, false><<<dim3(N1 / BN, M / BM), 256, 0, stream>>>(
            x, w_qkv, b_qkv, qkv, N1, K, K, N1);
        na1d_tiled_kernel<<<dim3(na_grid), 256, 0, stream>>>(qkv, rpb);
        gemm_bias_kernel<false, true, false><<<dim3(N2 / BN, M / BM), 256, 0, stream>>>(
            qkv, w_proj, b_proj, out, N2, K, N1, N2);
    }
}